// Round 3
// baseline (2219.300 us; speedup 1.0000x reference)
//
#include <hip/hip_runtime.h>
#include <hip/hip_bf16.h>

#define TWO_PI 6.28318530717958647692f

// dims
#define Bb 2
#define Ss 64
#define Dd 64
#define NH 8
#define HD 512
#define NM 256     // total modes (16x16)
#define CH 32      // modes per chunk
#define NCH 8      // chunks
#define BS 128     // B*S

// workspace offsets (bytes), total ~56.4 MiB
#define OFF_XM   0ull                        // bf16 [256][128][64][2]   8 MiB
#define OFF_WA   (OFF_XM + 8388608ull)       // bf16 [32][32768][2]      4 MiB
#define OFF_WB   (OFF_WA + 4194304ull)       // bf16 [32][32768][2]      4 MiB
#define OFF_QC   (OFF_WB + 4194304ull)       // bf16 [32][128][512][2]   8 MiB (also V chunk)
#define OFF_KC   (OFF_QC + 8388608ull)       // bf16 [32][128][512][2]   8 MiB (also SA chunk)
#define OFF_PART (OFF_KC + 8388608ull)       // f32  [32][16][64][64]    8 MiB
#define OFF_ATTN (OFF_PART + 8388608ull)     // f32  [16][64][64]
#define OFF_BIAS (OFF_ATTN + 262144ull)      // f32  [8][64][64]
#define OFF_OUTF (OFF_BIAS + 131072ull)      // f32  [256][128][64][2]  16 MiB
#define WS_TOTAL (OFF_OUTF + 16777216ull)

__device__ __forceinline__ float bl(unsigned u) { return __uint_as_float(u << 16); }
__device__ __forceinline__ float bhf(unsigned u) { return __uint_as_float(u & 0xffff0000u); }
__device__ __forceinline__ unsigned short f2b(float f) {
    unsigned u = __float_as_uint(f);
    return (unsigned short)((u + 0x7fffu + ((u >> 16) & 1u)) >> 16);
}
__device__ __forceinline__ unsigned pack2(float lo, float hi) {
    return (unsigned)f2b(lo) | ((unsigned)f2b(hi) << 16);
}

// ---------- weight layout transpose (chunk): in f32 [R=32768][256][2] -> out bf16 [CH][R][2] (modes m0..m0+CH-1)
__global__ __launch_bounds__(256) void k_transpose(const float* __restrict__ in,
                                                   unsigned short* __restrict__ outp, int m0) {
    __shared__ unsigned T[16][65];
    int tid = threadIdx.x;
    size_t r0 = (size_t)blockIdx.x * 64;
    int ml0 = blockIdx.y * 16;   // chunk-local mode base
    const float2* in2 = (const float2*)in;   // one complex per float2
    for (int p = 0; p < 4; ++p) {
        int f = tid + p * 256;
        int row = f >> 4, mc = f & 15;
        float2 v = in2[(r0 + row) * 256 + m0 + ml0 + mc];
        T[mc][row] = pack2(v.x, v.y);
    }
    __syncthreads();
    for (int p = 0; p < 4; ++p) {
        int f = tid + p * 256;
        int ml = f >> 6, rl = f & 63;
        ((unsigned*)outp)[(size_t)(ml0 + ml) * 32768 + r0 + rl] = T[ml][rl];
    }
}

// ---------- continuous position bias: bias[8][64][64]
__global__ void k_cpb(const float* __restrict__ w1, const float* __restrict__ b1,
                      const float* __restrict__ w2, float* __restrict__ bias) {
    int i = blockIdx.x, j = threadIdx.x;
    float dx = (float)((i >> 3) - (j >> 3));
    float dy = (float)((i & 7) - (j & 7));
    float rx = (dx > 0.f ? 1.f : (dx < 0.f ? -1.f : 0.f)) * log1pf(fabsf(dx));
    float ry = (dy > 0.f ? 1.f : (dy < 0.f ? -1.f : 0.f)) * log1pf(fabsf(dy));
    float acc[NH];
    for (int h = 0; h < NH; ++h) acc[h] = 0.f;
    for (int l = 0; l < Dd; ++l) {
        float hv = rx * w1[l] + ry * w1[Dd + l] + b1[l];
        hv = fmaxf(hv, 0.f);
        for (int h = 0; h < NH; ++h) acc[h] = fmaf(hv, w2[l * NH + h], acc[h]);
    }
    for (int h = 0; h < NH; ++h) bias[((size_t)h * Ss + i) * Ss + j] = acc[h];
}

// ---------- truncated rfft2 of seq (f32) -> XM bf16 [mode][bs][ci][2]
__global__ __launch_bounds__(256) void k_rfft(const float* __restrict__ seq,
                                              unsigned short* __restrict__ XM) {
    __shared__ float c32[32], s32[32];
    __shared__ float fld[32][33];
    __shared__ float tre[512], tim[512];  // [x][v] at x*16+v
    __shared__ float obuf[256][18];       // [mode][ci_local*2+reim]
    int tid = threadIdx.x;
    int cig = blockIdx.x;   // 0..7
    int bs = blockIdx.y;    // 0..127
    if (tid < 32) { float s, c; __sincosf(TWO_PI * tid / 32.0f, &s, &c); c32[tid] = c; s32[tid] = s; }
    for (int cl = 0; cl < 8; ++cl) {
        int ci = cig * 8 + cl;
        const float2* src = (const float2*)(seq + ((size_t)bs * Dd + ci) * 1024);
        for (int p = 0; p < 2; ++p) {
            int idx2 = tid + p * 256;                  // float2 index, 512 total
            float2 v = src[idx2];
            int x = idx2 >> 4, y2 = (idx2 & 15) * 2;
            fld[x][y2] = v.x; fld[x][y2 + 1] = v.y;
        }
        __syncthreads();
        for (int p = 0; p < 2; ++p) {   // stage1: t[x][v] = sum_y fld * e^{-i2pi vy/32}
            int e = tid + p * 256;
            int x = e >> 4, v = e & 15;
            float sr = 0.f, si = 0.f;
            for (int y = 0; y < 32; ++y) {
                float f = fld[x][y];
                int ph = (v * y) & 31;
                sr = fmaf(f, c32[ph], sr);
                si = fmaf(-f, s32[ph], si);
            }
            tre[x * 16 + v] = sr; tim[x * 16 + v] = si;
        }
        __syncthreads();
        {   // stage2: xm[u][v] = sum_x t[x][v] * e^{-i2pi ux/32}
            int u = tid >> 4, v = tid & 15;
            float xr = 0.f, xi = 0.f;
            for (int x = 0; x < 32; ++x) {
                float tr = tre[x * 16 + v], ti = tim[x * 16 + v];
                int ph = (u * x) & 31;
                float c = c32[ph], s = s32[ph];
                xr += tr * c + ti * s;
                xi += ti * c - tr * s;
            }
            obuf[tid][cl * 2] = xr; obuf[tid][cl * 2 + 1] = xi;
        }
        __syncthreads();
    }
    uint4 a, b;
    a.x = pack2(obuf[tid][0], obuf[tid][1]);
    a.y = pack2(obuf[tid][2], obuf[tid][3]);
    a.z = pack2(obuf[tid][4], obuf[tid][5]);
    a.w = pack2(obuf[tid][6], obuf[tid][7]);
    b.x = pack2(obuf[tid][8], obuf[tid][9]);
    b.y = pack2(obuf[tid][10], obuf[tid][11]);
    b.z = pack2(obuf[tid][12], obuf[tid][13]);
    b.w = pack2(obuf[tid][14], obuf[tid][15]);
    uint4* op = (uint4*)(XM + (((size_t)tid * 128 + bs) * 64 + cig * 8) * 2);
    op[0] = a; op[1] = b;
}

// ---------- per-mode complex GEMM (chunk): O[ml][bs][co] = XM[m0+ml] * W[ml], with Parseval scaling
// scale_kind 0: Q/K (sqrt2 family), 1: V (1/2 family)
__global__ __launch_bounds__(256) void k_modemix(const unsigned short* __restrict__ XM,
                                                 const unsigned short* __restrict__ W,
                                                 unsigned short* __restrict__ O,
                                                 int m0, int scale_kind) {
    __shared__ unsigned short Xs[128 * 130];
    __shared__ unsigned short Ws[64 * 130];
    int tid = threadIdx.x;
    int mode_l = blockIdx.x & (CH - 1);
    int cot = blockIdx.x >> 5;   // 0..7 (co block of 64)
    int mg = m0 + mode_l;        // global mode
    const unsigned short* Xg = XM + (size_t)mg * 16384;
    for (int p = 0; p < 8; ++p) {
        int g4 = tid + p * 256;
        int row = g4 >> 4, c4 = g4 & 15;
        uint4 v = *((const uint4*)(Xg + row * 128) + c4);
        unsigned* lp = (unsigned*)&Xs[row * 130 + c4 * 8];
        lp[0] = v.x; lp[1] = v.y; lp[2] = v.z; lp[3] = v.w;
    }
    const unsigned short* Wg = W + (size_t)mode_l * 65536u + cot * 128;
    for (int p = 0; p < 4; ++p) {
        int g4 = tid + p * 256;
        int ci = g4 >> 4, c4 = g4 & 15;          // 64 rows x 16 uint4
        uint4 v = *((const uint4*)(Wg + ci * 1024) + c4);
        unsigned* lp = (unsigned*)&Ws[ci * 130 + c4 * 8];
        lp[0] = v.x; lp[1] = v.y; lp[2] = v.z; lp[3] = v.w;
    }
    __syncthreads();
    int tx = tid & 15, ty = tid >> 4;
    int i0 = ty * 8, c0 = tx * 4;
    float ar[8][4] = {}, ai[8][4] = {};
    const unsigned* Xu = (const unsigned*)Xs;
    const unsigned* Wu = (const unsigned*)Ws;
    for (int k = 0; k < 64; ++k) {
        float xr[8], xi_[8], wr[4], wi[4];
        for (int r = 0; r < 8; ++r) { unsigned u = Xu[(i0 + r) * 65 + k]; xr[r] = bl(u); xi_[r] = bhf(u); }
        for (int c = 0; c < 4; ++c) { unsigned u = Wu[k * 65 + c0 + c]; wr[c] = bl(u); wi[c] = bhf(u); }
        for (int r = 0; r < 8; ++r)
            for (int c = 0; c < 4; ++c) {
                ar[r][c] = fmaf(xr[r], wr[c], ar[r][c]);
                ar[r][c] = fmaf(-xi_[r], wi[c], ar[r][c]);
                ai[r][c] = fmaf(xr[r], wi[c], ai[r][c]);
                ai[r][c] = fmaf(xi_[r], wr[c], ai[r][c]);
            }
    }
    int u = mg >> 4, v = mg & 15;
    float scr, sci;
    if (scale_kind == 0) {
        if (v > 0)      { scr = 1.41421356f; sci = 1.41421356f; }
        else if (u > 0) { scr = 0.70710678f; sci = 0.70710678f; }
        else            { scr = 1.f; sci = 0.f; }
    } else {
        if (v > 0)      { scr = 1.f; sci = 1.f; }
        else if (u > 0) { scr = 0.5f; sci = 0.5f; }
        else            { scr = 1.f; sci = 0.f; }
    }
    for (int r = 0; r < 8; ++r) {
        int i = i0 + r;
        uint4 val;
        val.x = pack2(ar[r][0] * scr, ai[r][0] * sci);
        val.y = pack2(ar[r][1] * scr, ai[r][1] * sci);
        val.z = pack2(ar[r][2] * scr, ai[r][2] * sci);
        val.w = pack2(ar[r][3] * scr, ai[r][3] * sci);
        *((uint4*)(O + (((size_t)mode_l * 128 + i) * 512 + cot * 64 + c0) * 2)) = val;
    }
}

// ---------- scores partials (chunk): part[c*4+mgl][bh][i][j] = sum over 8 modes of Qt . Kt
__global__ __launch_bounds__(256) void k_scores(const unsigned short* __restrict__ Q,
                                                const unsigned short* __restrict__ Kk,
                                                float* __restrict__ part, int c) {
    __shared__ unsigned short Qs[64 * 130], Ks[64 * 130];
    int tid = threadIdx.x;
    int mgl = blockIdx.x;  // 0..3
    int bh = blockIdx.y;   // 0..15
    int b = bh >> 3, h = bh & 7;
    int tx = tid & 15, ty = tid >> 4;
    float acc[4][4] = {};
    for (int mm = 0; mm < 8; ++mm) {
        int mode_l = mgl * 8 + mm;
        size_t base = (((size_t)mode_l * 128 + b * 64) * 512 + h * 64) * 2;
        for (int p = 0; p < 4; ++p) {
            int g4 = tid + p * 256;
            int i = g4 >> 4, c4 = g4 & 15;
            uint4 qv = *((const uint4*)(Q + base + i * 1024) + c4);
            unsigned* lp = (unsigned*)&Qs[i * 130 + c4 * 8];
            lp[0] = qv.x; lp[1] = qv.y; lp[2] = qv.z; lp[3] = qv.w;
            uint4 kv = *((const uint4*)(Kk + base + i * 1024) + c4);
            unsigned* lp2 = (unsigned*)&Ks[i * 130 + c4 * 8];
            lp2[0] = kv.x; lp2[1] = kv.y; lp2[2] = kv.z; lp2[3] = kv.w;
        }
        __syncthreads();
        const unsigned* Qu = (const unsigned*)Qs;
        const unsigned* Ku = (const unsigned*)Ks;
        for (int k2 = 0; k2 < 64; ++k2) {
            float qlo[4], qhi[4], klo[4], khi[4];
            for (int r = 0; r < 4; ++r) { unsigned u = Qu[(ty * 4 + r) * 65 + k2]; qlo[r] = bl(u); qhi[r] = bhf(u); }
            for (int cc = 0; cc < 4; ++cc) { unsigned u = Ku[(tx * 4 + cc) * 65 + k2]; klo[cc] = bl(u); khi[cc] = bhf(u); }
            for (int r = 0; r < 4; ++r)
                for (int cc = 0; cc < 4; ++cc) {
                    acc[r][cc] = fmaf(qlo[r], klo[cc], acc[r][cc]);
                    acc[r][cc] = fmaf(qhi[r], khi[cc], acc[r][cc]);
                }
        }
        __syncthreads();
    }
    float* pp = part + (((size_t)(c * 4 + mgl) * 16 + bh) * 64) * 64;
    for (int r = 0; r < 4; ++r)
        for (int cc = 0; cc < 4; ++cc)
            pp[(ty * 4 + r) * 64 + tx * 4 + cc] = acc[r][cc];
}

// ---------- reduce partials + bias + softmax -> attn[bh][i][j] f32
__global__ void k_softmax(const float* __restrict__ part, const float* __restrict__ bias,
                          float* __restrict__ attn) {
    int j = threadIdx.x;   // 64
    int i = blockIdx.x;    // 64
    int bh = blockIdx.y;   // 16
    int h = bh & 7;
    float s = 0.f;
    for (int mg = 0; mg < 32; ++mg)
        s += part[(((size_t)mg * 16 + bh) * 64 + i) * 64 + j];
    s = s * (1.0f / 262144.0f) + bias[((size_t)h * 64 + i) * 64 + j];
    float m = s;
    for (int o = 32; o >= 1; o >>= 1) m = fmaxf(m, __shfl_xor(m, o));
    float e = expf(s - m);
    float t = e;
    for (int o = 32; o >= 1; o >>= 1) t += __shfl_xor(t, o);
    attn[((size_t)bh * 64 + i) * 64 + j] = e / t;
}

// ---------- SA chunk: SA[ml][b*64+i][h*64+d] = sum_j attn[b,h,i,j] * Vt[ml][b*64+j][h*64+d]
__global__ __launch_bounds__(256) void k_sa(const float* __restrict__ attn,
                                            const unsigned short* __restrict__ V,
                                            unsigned short* __restrict__ SA) {
    __shared__ float As[64 * 65];
    __shared__ unsigned short Vs[64 * 130];
    int tid = threadIdx.x;
    int mode_l = blockIdx.x;   // 0..CH-1
    int bh = blockIdx.y; int b = bh >> 3, h = bh & 7;
    for (int p = 0; p < 16; ++p) {
        int g = tid + p * 256; int i = g >> 6, j = g & 63;
        As[i * 65 + j] = attn[((size_t)bh * 64 + i) * 64 + j];
    }
    size_t base = (((size_t)mode_l * 128 + b * 64) * 512 + h * 64) * 2;
    for (int p = 0; p < 4; ++p) {
        int g4 = tid + p * 256; int jj = g4 >> 4, c4 = g4 & 15;
        uint4 vv = *((const uint4*)(V + base + jj * 1024) + c4);
        unsigned* lp = (unsigned*)&Vs[jj * 130 + c4 * 8];
        lp[0] = vv.x; lp[1] = vv.y; lp[2] = vv.z; lp[3] = vv.w;
    }
    __syncthreads();
    int tx = tid & 15, ty = tid >> 4;
    float acc[4][8] = {};
    const unsigned* Vu = (const unsigned*)Vs;
    for (int j = 0; j < 64; ++j) {
        float a[4];
        for (int r = 0; r < 4; ++r) a[r] = As[(ty * 4 + r) * 65 + j];
        for (int cc = 0; cc < 4; ++cc) {
            unsigned u = Vu[j * 65 + tx * 4 + cc];
            float lo = bl(u), hi = bhf(u);
            for (int r = 0; r < 4; ++r) {
                acc[r][cc * 2] = fmaf(a[r], lo, acc[r][cc * 2]);
                acc[r][cc * 2 + 1] = fmaf(a[r], hi, acc[r][cc * 2 + 1]);
            }
        }
    }
    for (int r = 0; r < 4; ++r) {
        int i = ty * 4 + r;
        uint4 val;
        val.x = pack2(acc[r][0], acc[r][1]);
        val.y = pack2(acc[r][2], acc[r][3]);
        val.z = pack2(acc[r][4], acc[r][5]);
        val.w = pack2(acc[r][6], acc[r][7]);
        *((uint4*)(SA + base + i * 1024 + tx * 8)) = val;
    }
}

// ---------- outf[m0+ml][bs][c2] f32 (complex) = sum_co SA[ml][bs][co] * WTo[ml][co][c2]
__global__ __launch_bounds__(256) void k_wo(const unsigned short* __restrict__ SA,
                                            const unsigned short* __restrict__ WT3,
                                            float* __restrict__ outf, int m0) {
    __shared__ unsigned short SAs[128 * 130];
    __shared__ unsigned short Ws[64 * 130];
    int tid = threadIdx.x;
    int mode_l = blockIdx.x;
    int tx = tid & 15, ty = tid >> 4;
    float ar[8][4] = {}, ai[8][4] = {};
    for (int kc = 0; kc < 8; ++kc) {
        for (int p = 0; p < 8; ++p) {
            int g4 = tid + p * 256; int i = g4 >> 4, c4 = g4 & 15;
            uint4 v = *((const uint4*)(SA + (((size_t)mode_l * 128 + i) * 512 + kc * 64) * 2) + c4);
            unsigned* lp = (unsigned*)&SAs[i * 130 + c4 * 8];
            lp[0] = v.x; lp[1] = v.y; lp[2] = v.z; lp[3] = v.w;
        }
        for (int p = 0; p < 4; ++p) {
            int g4 = tid + p * 256; int cl = g4 >> 4, c4 = g4 & 15;
            uint4 v = *((const uint4*)(WT3 + (size_t)mode_l * 65536 + (size_t)(kc * 64 + cl) * 128) + c4);
            unsigned* lp = (unsigned*)&Ws[cl * 130 + c4 * 8];
            lp[0] = v.x; lp[1] = v.y; lp[2] = v.z; lp[3] = v.w;
        }
        __syncthreads();
        const unsigned* Xu = (const unsigned*)SAs;
        const unsigned* Wu = (const unsigned*)Ws;
        for (int k = 0; k < 64; ++k) {
            float xr[8], xi_[8], wr[4], wi[4];
            for (int r = 0; r < 8; ++r) { unsigned u = Xu[(ty * 8 + r) * 65 + k]; xr[r] = bl(u); xi_[r] = bhf(u); }
            for (int c = 0; c < 4; ++c) { unsigned u = Wu[k * 65 + tx * 4 + c]; wr[c] = bl(u); wi[c] = bhf(u); }
            for (int r = 0; r < 8; ++r)
                for (int c = 0; c < 4; ++c) {
                    ar[r][c] = fmaf(xr[r], wr[c], ar[r][c]);
                    ar[r][c] = fmaf(-xi_[r], wi[c], ar[r][c]);
                    ai[r][c] = fmaf(xr[r], wi[c], ai[r][c]);
                    ai[r][c] = fmaf(xi_[r], wr[c], ai[r][c]);
                }
        }
        __syncthreads();
    }
    for (int r = 0; r < 8; ++r) {
        int i = ty * 8 + r;
        float4 v0 = {ar[r][0], ai[r][0], ar[r][1], ai[r][1]};
        float4 v1 = {ar[r][2], ai[r][2], ar[r][3], ai[r][3]};
        float4* op = (float4*)(outf + (((size_t)(m0 + mode_l) * 128 + i) * 64 + tx * 4) * 2);
        op[0] = v0; op[1] = v1;
    }
}

// ---------- custom irfft2 of padded outf -> out f32 [bs][c2][32][32]
__global__ __launch_bounds__(256) void k_irfft(const float* __restrict__ outf,
                                               float* __restrict__ out) {
    __shared__ float c32[32], s32[32];
    __shared__ float mf[256][18];    // [mode][c2local*2+reim]
    __shared__ float sr[16 * 33], si[16 * 33];
    int tid = threadIdx.x;
    int cg = blockIdx.x;   // 0..7
    int bs = blockIdx.y;   // 0..127
    if (tid < 32) { float s, c; __sincosf(TWO_PI * tid / 32.0f, &s, &c); c32[tid] = c; s32[tid] = s; }
    {
        const float4* gp = (const float4*)(outf + (((size_t)tid * 128 + bs) * 64 + cg * 8) * 2);
        for (int q = 0; q < 4; ++q) {
            float4 v = gp[q];
            mf[tid][q * 4 + 0] = v.x; mf[tid][q * 4 + 1] = v.y;
            mf[tid][q * 4 + 2] = v.z; mf[tid][q * 4 + 3] = v.w;
        }
    }
    __syncthreads();
    for (int cc = 0; cc < 8; ++cc) {
        for (int p = 0; p < 2; ++p) {   // stage1: s'[u][y] = 0.5*f[u][0] + sum_{v>=1} f * e^{+i2pi vy/32}
            int e = tid + p * 256;
            int u = e >> 5, y = e & 31;
            float fr0 = mf[u * 16][cc * 2];
            float fi0 = (u == 0) ? 0.f : mf[u * 16][cc * 2 + 1];
            float ssr = 0.5f * fr0, ssi = 0.5f * fi0;
            for (int v = 1; v < 16; ++v) {
                float fr = mf[u * 16 + v][cc * 2], fi = mf[u * 16 + v][cc * 2 + 1];
                int ph = (v * y) & 31;
                float c = c32[ph], s = s32[ph];
                ssr += fr * c - fi * s;
                ssi += fr * s + fi * c;
            }
            sr[u * 33 + y] = ssr; si[u * 33 + y] = ssi;
        }
        __syncthreads();
        float res[4];
        for (int p = 0; p < 4; ++p) {   // stage2: out = (1/512) sum_u Re{s' e^{+i2pi ux/32}}
            int pos = tid + p * 256;
            int x = pos >> 5, y = pos & 31;
            float acc = 0.f;
            for (int u = 0; u < 16; ++u) {
                int ph = (u * x) & 31;
                acc += sr[u * 33 + y] * c32[ph] - si[u * 33 + y] * s32[ph];
            }
            res[p] = acc * (1.0f / 512.0f);
        }
        float* op = out + ((size_t)(bs * 64 + cg * 8 + cc)) * 1024;
        for (int p = 0; p < 4; ++p) op[tid + p * 256] = res[p];
        __syncthreads();
    }
}

extern "C" void kernel_launch(void* const* d_in, const int* in_sizes, int n_in,
                              void* d_out, int out_size, void* d_ws, size_t ws_size,
                              hipStream_t stream) {
    (void)in_sizes; (void)n_in; (void)out_size;
    const float* seq = (const float*)d_in[0];
    const float* wq = (const float*)d_in[1];
    const float* wk = (const float*)d_in[2];
    const float* wv = (const float*)d_in[3];
    const float* wo = (const float*)d_in[4];
    const float* cw1 = (const float*)d_in[5];
    const float* cb1 = (const float*)d_in[6];
    const float* cw2 = (const float*)d_in[7];
    float* out = (float*)d_out;
    char* ws = (char*)d_ws;
    if (ws_size < WS_TOTAL) return;

    unsigned short* XM = (unsigned short*)(ws + OFF_XM);
    unsigned short* WA = (unsigned short*)(ws + OFF_WA);
    unsigned short* WB = (unsigned short*)(ws + OFF_WB);
    unsigned short* QC = (unsigned short*)(ws + OFF_QC);
    unsigned short* KC = (unsigned short*)(ws + OFF_KC);
    float* PART = (float*)(ws + OFF_PART);
    float* ATTN = (float*)(ws + OFF_ATTN);
    float* BIAS = (float*)(ws + OFF_BIAS);
    float* OUTF = (float*)(ws + OFF_OUTF);

    k_cpb<<<dim3(64), dim3(64), 0, stream>>>(cw1, cb1, cw2, BIAS);
    k_rfft<<<dim3(8, 128), dim3(256), 0, stream>>>(seq, XM);

    // phase 1: per chunk, Q/K then partial scores
    for (int c = 0; c < NCH; ++c) {
        int m0 = c * CH;
        k_transpose<<<dim3(512, CH / 16), dim3(256), 0, stream>>>(wq, WA, m0);
        k_transpose<<<dim3(512, CH / 16), dim3(256), 0, stream>>>(wk, WB, m0);
        k_modemix<<<dim3(CH * 8), dim3(256), 0, stream>>>(XM, WA, QC, m0, 0);
        k_modemix<<<dim3(CH * 8), dim3(256), 0, stream>>>(XM, WB, KC, m0, 0);
        k_scores<<<dim3(CH / 8, 16), dim3(256), 0, stream>>>(QC, KC, PART, c);
    }
    k_softmax<<<dim3(64, 16), dim3(64), 0, stream>>>(PART, BIAS, ATTN);

    // phase 2: per chunk, V -> attn*V -> wo -> OUTF slice
    for (int c = 0; c < NCH; ++c) {
        int m0 = c * CH;
        k_transpose<<<dim3(512, CH / 16), dim3(256), 0, stream>>>(wv, WA, m0);
        k_modemix<<<dim3(CH * 8), dim3(256), 0, stream>>>(XM, WA, QC, m0, 1);   // QC holds V chunk
        k_sa<<<dim3(CH, 16), dim3(256), 0, stream>>>(ATTN, QC, KC);             // KC holds SA chunk
        k_transpose<<<dim3(512, CH / 16), dim3(256), 0, stream>>>(wo, WB, m0);
        k_wo<<<dim3(CH), dim3(256), 0, stream>>>(KC, WB, OUTF, m0);
    }
    k_irfft<<<dim3(8, 128), dim3(256), 0, stream>>>(OUTF, out);
}

// Round 4
// 874.767 us; speedup vs baseline: 2.5370x; 2.5370x over previous
//
#include <hip/hip_runtime.h>

#define TWO_PI 6.28318530717958647692f

// dims
#define NH 8
#define CH 128     // modes per chunk
#define NCH 2

// workspace offsets (bytes), total ~56.25 MiB (<= proven-safe 56.4 MiB)
#define OFF_XM   0ull                        // bf16 [256][128][64][2]   8 MiB
#define OFF_WTA  (OFF_XM + 8388608ull)       // bf16 [128][32768][2]    16 MiB
#define OFF_WTB  (OFF_WTA + 16777216ull)     // bf16 [128][32768][2]    16 MiB
#define OFF_PO   (OFF_WTB + 16777216ull)     // f32: PART [64][16][64][64] / OUTF [256][128][64][2]  16 MiB (shared)
#define OFF_ATTN (OFF_PO + 16777216ull)      // f32 [16][64][64]
#define WS_TOTAL (OFF_ATTN + 262144ull)

__device__ __forceinline__ float bl(unsigned u) { return __uint_as_float(u << 16); }
__device__ __forceinline__ float bhf(unsigned u) { return __uint_as_float(u & 0xffff0000u); }
__device__ __forceinline__ unsigned short f2b(float f) {
    unsigned u = __float_as_uint(f);
    return (unsigned short)((u + 0x7fffu + ((u >> 16) & 1u)) >> 16);
}
__device__ __forceinline__ unsigned pack2(float lo, float hi) {
    return (unsigned)f2b(lo) | ((unsigned)f2b(hi) << 16);
}

// ---------- weight layout transpose (chunk): in f32 [R=32768][256][2] -> out bf16 [CH][R][2] (modes m0..m0+CH-1)
__global__ __launch_bounds__(256) void k_transpose(const float* __restrict__ in,
                                                   unsigned short* __restrict__ outp, int m0) {
    __shared__ unsigned T[16][65];
    int tid = threadIdx.x;
    size_t r0 = (size_t)blockIdx.x * 64;
    int ml0 = blockIdx.y * 16;   // chunk-local mode base
    const float2* in2 = (const float2*)in;   // one complex per float2
    for (int p = 0; p < 4; ++p) {
        int f = tid + p * 256;
        int row = f >> 4, mc = f & 15;
        float2 v = in2[(r0 + row) * 256 + m0 + ml0 + mc];
        T[mc][row] = pack2(v.x, v.y);
    }
    __syncthreads();
    for (int p = 0; p < 4; ++p) {
        int f = tid + p * 256;
        int ml = f >> 6, rl = f & 63;
        ((unsigned*)outp)[(size_t)(ml0 + ml) * 32768 + r0 + rl] = T[ml][rl];
    }
}

// ---------- truncated rfft2 of seq (f32) -> XM bf16 [mode][bs][ci][2]
__global__ __launch_bounds__(256) void k_rfft(const float* __restrict__ seq,
                                              unsigned short* __restrict__ XM) {
    __shared__ float c32[32], s32[32];
    __shared__ float fld[32][33];
    __shared__ float tre[512], tim[512];  // [x][v] at x*16+v
    __shared__ float obuf[256][18];       // [mode][ci_local*2+reim]
    int tid = threadIdx.x;
    int cig = blockIdx.x;   // 0..7
    int bs = blockIdx.y;    // 0..127
    if (tid < 32) { float s, c; __sincosf(TWO_PI * tid / 32.0f, &s, &c); c32[tid] = c; s32[tid] = s; }
    for (int cl = 0; cl < 8; ++cl) {
        int ci = cig * 8 + cl;
        const float2* src = (const float2*)(seq + ((size_t)bs * 64 + ci) * 1024);
        for (int p = 0; p < 2; ++p) {
            int idx2 = tid + p * 256;                  // float2 index, 512 total
            float2 v = src[idx2];
            int x = idx2 >> 4, y2 = (idx2 & 15) * 2;
            fld[x][y2] = v.x; fld[x][y2 + 1] = v.y;
        }
        __syncthreads();
        for (int p = 0; p < 2; ++p) {   // stage1: t[x][v] = sum_y fld * e^{-i2pi vy/32}
            int e = tid + p * 256;
            int x = e >> 4, v = e & 15;
            float sr = 0.f, si = 0.f;
            for (int y = 0; y < 32; ++y) {
                float f = fld[x][y];
                int ph = (v * y) & 31;
                sr = fmaf(f, c32[ph], sr);
                si = fmaf(-f, s32[ph], si);
            }
            tre[x * 16 + v] = sr; tim[x * 16 + v] = si;
        }
        __syncthreads();
        {   // stage2: xm[u][v] = sum_x t[x][v] * e^{-i2pi ux/32}
            int u = tid >> 4, v = tid & 15;
            float xr = 0.f, xi = 0.f;
            for (int x = 0; x < 32; ++x) {
                float tr = tre[x * 16 + v], ti = tim[x * 16 + v];
                int ph = (u * x) & 31;
                float c = c32[ph], s = s32[ph];
                xr += tr * c + ti * s;
                xi += ti * c - tr * s;
            }
            obuf[tid][cl * 2] = xr; obuf[tid][cl * 2 + 1] = xi;
        }
        __syncthreads();
    }
    uint4 a, b;
    a.x = pack2(obuf[tid][0], obuf[tid][1]);
    a.y = pack2(obuf[tid][2], obuf[tid][3]);
    a.z = pack2(obuf[tid][4], obuf[tid][5]);
    a.w = pack2(obuf[tid][6], obuf[tid][7]);
    b.x = pack2(obuf[tid][8], obuf[tid][9]);
    b.y = pack2(obuf[tid][10], obuf[tid][11]);
    b.z = pack2(obuf[tid][12], obuf[tid][13]);
    b.w = pack2(obuf[tid][14], obuf[tid][15]);
    uint4* op = (uint4*)(XM + (((size_t)tid * 128 + bs) * 64 + cig * 8) * 2);
    op[0] = a; op[1] = b;
}

// ---------- fused Q/K modemix + scores (chunk): block=(mg of 4 modes, h, b)
// part[mgG][b*8+h][i][j] = sum over 4 modes of Qtilde . Ktilde
__global__ __launch_bounds__(256) void k_qks(const unsigned short* __restrict__ XM,
                                             const unsigned short* __restrict__ WQ,
                                             const unsigned short* __restrict__ WK,
                                             float* __restrict__ part, int mbase) {
    __shared__ unsigned short Xs[64 * 130];
    __shared__ unsigned short Ws[64 * 130];
    __shared__ unsigned short Qs[64 * 130];
    __shared__ unsigned short Ks[64 * 130];
    int tid = threadIdx.x;
    int mg = blockIdx.x;      // 0..31
    int h = blockIdx.y;       // 0..7
    int b = blockIdx.z;       // 0..1
    int tx = tid & 15, ty = tid >> 4;
    float sacc[4][4] = {};
    for (int mm = 0; mm < 4; ++mm) {
        int ml = mg * 4 + mm;          // chunk-local mode
        int mode = mbase + ml;         // global mode
        int mu = mode >> 4, mv = mode & 15;
        float scr, sci;
        if (mv > 0)      { scr = 1.41421356f; sci = 1.41421356f; }
        else if (mu > 0) { scr = 0.70710678f; sci = 0.70710678f; }
        else             { scr = 1.f; sci = 0.f; }
        __syncthreads();
        // stage Xs: rows j 0..63 (bs = b*64+j), cols ci 0..63
        for (int p = 0; p < 4; ++p) {
            int g4 = tid + p * 256; int row = g4 >> 4, c4 = g4 & 15;
            uint4 v = *((const uint4*)(XM + ((size_t)mode * 128 + b * 64 + row) * 128) + c4);
            unsigned* lp = (unsigned*)&Xs[row * 130 + c4 * 8];
            lp[0] = v.x; lp[1] = v.y; lp[2] = v.z; lp[3] = v.w;
        }
        // stage Ws = WQ tile: rows ci, cols co=h*64..+64
        for (int p = 0; p < 4; ++p) {
            int g4 = tid + p * 256; int ci = g4 >> 4, c4 = g4 & 15;
            uint4 v = *((const uint4*)(WQ + ((size_t)ml * 32768 + ci * 512 + h * 64) * 2) + c4);
            unsigned* lp = (unsigned*)&Ws[ci * 130 + c4 * 8];
            lp[0] = v.x; lp[1] = v.y; lp[2] = v.z; lp[3] = v.w;
        }
        __syncthreads();
        {   // Qtilde = Xs * WQ, scaled, -> Qs
            float ar[4][4] = {}, ai[4][4] = {};
            const unsigned* Xu = (const unsigned*)Xs;
            const unsigned* Wu = (const unsigned*)Ws;
            for (int k = 0; k < 64; ++k) {
                float xr[4], xi_[4], wr[4], wi[4];
                for (int r = 0; r < 4; ++r) { unsigned u = Xu[(ty * 4 + r) * 65 + k]; xr[r] = bl(u); xi_[r] = bhf(u); }
                for (int c = 0; c < 4; ++c) { unsigned u = Wu[k * 65 + tx * 4 + c]; wr[c] = bl(u); wi[c] = bhf(u); }
                for (int r = 0; r < 4; ++r)
                    for (int c = 0; c < 4; ++c) {
                        ar[r][c] = fmaf(xr[r], wr[c], ar[r][c]);
                        ar[r][c] = fmaf(-xi_[r], wi[c], ar[r][c]);
                        ai[r][c] = fmaf(xr[r], wi[c], ai[r][c]);
                        ai[r][c] = fmaf(xi_[r], wr[c], ai[r][c]);
                    }
            }
            for (int r = 0; r < 4; ++r)
                for (int c = 0; c < 4; ++c)
                    ((unsigned*)Qs)[(ty * 4 + r) * 65 + tx * 4 + c] = pack2(ar[r][c] * scr, ai[r][c] * sci);
        }
        __syncthreads();
        // stage Ws = WK tile
        for (int p = 0; p < 4; ++p) {
            int g4 = tid + p * 256; int ci = g4 >> 4, c4 = g4 & 15;
            uint4 v = *((const uint4*)(WK + ((size_t)ml * 32768 + ci * 512 + h * 64) * 2) + c4);
            unsigned* lp = (unsigned*)&Ws[ci * 130 + c4 * 8];
            lp[0] = v.x; lp[1] = v.y; lp[2] = v.z; lp[3] = v.w;
        }
        __syncthreads();
        {   // Ktilde -> Ks
            float ar[4][4] = {}, ai[4][4] = {};
            const unsigned* Xu = (const unsigned*)Xs;
            const unsigned* Wu = (const unsigned*)Ws;
            for (int k = 0; k < 64; ++k) {
                float xr[4], xi_[4], wr[4], wi[4];
                for (int r = 0; r < 4; ++r) { unsigned u = Xu[(ty * 4 + r) * 65 + k]; xr[r] = bl(u); xi_[r] = bhf(u); }
                for (int c = 0; c < 4; ++c) { unsigned u = Wu[k * 65 + tx * 4 + c]; wr[c] = bl(u); wi[c] = bhf(u); }
                for (int r = 0; r < 4; ++r)
                    for (int c = 0; c < 4; ++c) {
                        ar[r][c] = fmaf(xr[r], wr[c], ar[r][c]);
                        ar[r][c] = fmaf(-xi_[r], wi[c], ar[r][c]);
                        ai[r][c] = fmaf(xr[r], wi[c], ai[r][c]);
                        ai[r][c] = fmaf(xi_[r], wr[c], ai[r][c]);
                    }
            }
            for (int r = 0; r < 4; ++r)
                for (int c = 0; c < 4; ++c)
                    ((unsigned*)Ks)[(ty * 4 + r) * 65 + tx * 4 + c] = pack2(ar[r][c] * scr, ai[r][c] * sci);
        }
        __syncthreads();
        {   // scores: sacc[i][j] += sum_d Qt[i,d].Kt[j,d] (real dot over re/im)
            const unsigned* Qu = (const unsigned*)Qs;
            const unsigned* Ku = (const unsigned*)Ks;
            for (int k2 = 0; k2 < 64; ++k2) {
                float ql[4], qh[4], kl[4], kh[4];
                for (int r = 0; r < 4; ++r) { unsigned u = Qu[(ty * 4 + r) * 65 + k2]; ql[r] = bl(u); qh[r] = bhf(u); }
                for (int c = 0; c < 4; ++c) { unsigned u = Ku[(tx * 4 + c) * 65 + k2]; kl[c] = bl(u); kh[c] = bhf(u); }
                for (int r = 0; r < 4; ++r)
                    for (int c = 0; c < 4; ++c) {
                        sacc[r][c] = fmaf(ql[r], kl[c], sacc[r][c]);
                        sacc[r][c] = fmaf(qh[r], kh[c], sacc[r][c]);
                    }
            }
        }
    }
    int mgG = (mbase >> 2) + mg;   // 0..63
    float* pp = part + (((size_t)mgG * 16 + b * 8 + h) * 64) * 64;
    for (int r = 0; r < 4; ++r)
        for (int c = 0; c < 4; ++c)
            pp[(ty * 4 + r) * 64 + tx * 4 + c] = sacc[r][c];
}

// ---------- reduce partials + inline CPB bias + softmax -> attn[bh][i][j] f32
__global__ void k_softmax(const float* __restrict__ part,
                          const float* __restrict__ w1, const float* __restrict__ b1,
                          const float* __restrict__ w2, float* __restrict__ attn) {
    int j = threadIdx.x;   // 64
    int i = blockIdx.x;    // 64
    int bh = blockIdx.y;   // 16
    int h = bh & 7;
    float s = 0.f;
    for (int mg = 0; mg < 64; ++mg)
        s += part[(((size_t)mg * 16 + bh) * 64 + i) * 64 + j];
    float dx = (float)((i >> 3) - (j >> 3));
    float dy = (float)((i & 7) - (j & 7));
    float rx = (dx > 0.f ? 1.f : (dx < 0.f ? -1.f : 0.f)) * log1pf(fabsf(dx));
    float ry = (dy > 0.f ? 1.f : (dy < 0.f ? -1.f : 0.f)) * log1pf(fabsf(dy));
    float bias = 0.f;
    for (int l = 0; l < 64; ++l) {
        float hv = fmaxf(rx * w1[l] + ry * w1[64 + l] + b1[l], 0.f);
        bias = fmaf(hv, w2[l * NH + h], bias);
    }
    s = s * (1.0f / 262144.0f) + bias;
    float m = s;
    for (int o = 32; o >= 1; o >>= 1) m = fmaxf(m, __shfl_xor(m, o));
    float e = expf(s - m);
    float t = e;
    for (int o = 32; o >= 1; o >>= 1) t += __shfl_xor(t, o);
    attn[((size_t)bh * 64 + i) * 64 + j] = e / t;
}

// ---------- fused V modemix + attn*V + wo (chunk): block=(mode_local, b)
// outf[mode][b*64+i][c2] f32 complex = sum_h sum_{d in h} (sum_j attn[b,h,i,j] Vt[j,d]) * WO[d][c2]
__global__ __launch_bounds__(256) void k_savo(const unsigned short* __restrict__ XM,
                                              const unsigned short* __restrict__ WV,
                                              const unsigned short* __restrict__ WO,
                                              const float* __restrict__ attn,
                                              float* __restrict__ outf, int mbase) {
    __shared__ unsigned short Xs[64 * 130];
    __shared__ unsigned short Ws[64 * 130];
    __shared__ unsigned short Vs[64 * 130];
    __shared__ unsigned short SAs[64 * 130];
    __shared__ float As[64 * 65];
    int tid = threadIdx.x;
    int ml = blockIdx.x;      // 0..CH-1
    int b = blockIdx.y;       // 0..1
    int mode = mbase + ml;
    int tx = tid & 15, ty = tid >> 4;
    int mu = mode >> 4, mv = mode & 15;
    float scr, sci;
    if (mv > 0)      { scr = 1.f; sci = 1.f; }
    else if (mu > 0) { scr = 0.5f; sci = 0.5f; }
    else             { scr = 1.f; sci = 0.f; }
    // stage Xs once: rows j 0..63 (bs=b*64+j), cols ci
    for (int p = 0; p < 4; ++p) {
        int g4 = tid + p * 256; int row = g4 >> 4, c4 = g4 & 15;
        uint4 v = *((const uint4*)(XM + ((size_t)mode * 128 + b * 64 + row) * 128) + c4);
        unsigned* lp = (unsigned*)&Xs[row * 130 + c4 * 8];
        lp[0] = v.x; lp[1] = v.y; lp[2] = v.z; lp[3] = v.w;
    }
    float oar[4][4] = {}, oai[4][4] = {};
    for (int h = 0; h < NH; ++h) {
        __syncthreads();
        // stage Ws = WV tile (rows ci, cols h*64..+64) and As = attn[b,h]
        for (int p = 0; p < 4; ++p) {
            int g4 = tid + p * 256; int ci = g4 >> 4, c4 = g4 & 15;
            uint4 v = *((const uint4*)(WV + ((size_t)ml * 32768 + ci * 512 + h * 64) * 2) + c4);
            unsigned* lp = (unsigned*)&Ws[ci * 130 + c4 * 8];
            lp[0] = v.x; lp[1] = v.y; lp[2] = v.z; lp[3] = v.w;
        }
        for (int p = 0; p < 16; ++p) {
            int g = tid + p * 256; int i = g >> 6, j = g & 63;
            As[i * 65 + j] = attn[((size_t)(b * 8 + h) * 64 + i) * 64 + j];
        }
        __syncthreads();
        {   // Vtilde = Xs * WV, scaled -> Vs
            float ar[4][4] = {}, ai[4][4] = {};
            const unsigned* Xu = (const unsigned*)Xs;
            const unsigned* Wu = (const unsigned*)Ws;
            for (int k = 0; k < 64; ++k) {
                float xr[4], xi_[4], wr[4], wi[4];
                for (int r = 0; r < 4; ++r) { unsigned u = Xu[(ty * 4 + r) * 65 + k]; xr[r] = bl(u); xi_[r] = bhf(u); }
                for (int c = 0; c < 4; ++c) { unsigned u = Wu[k * 65 + tx * 4 + c]; wr[c] = bl(u); wi[c] = bhf(u); }
                for (int r = 0; r < 4; ++r)
                    for (int c = 0; c < 4; ++c) {
                        ar[r][c] = fmaf(xr[r], wr[c], ar[r][c]);
                        ar[r][c] = fmaf(-xi_[r], wi[c], ar[r][c]);
                        ai[r][c] = fmaf(xr[r], wi[c], ai[r][c]);
                        ai[r][c] = fmaf(xi_[r], wr[c], ai[r][c]);
                    }
            }
            for (int r = 0; r < 4; ++r)
                for (int c = 0; c < 4; ++c)
                    ((unsigned*)Vs)[(ty * 4 + r) * 65 + tx * 4 + c] = pack2(ar[r][c] * scr, ai[r][c] * sci);
        }
        __syncthreads();
        // stage Ws = WO tile: rows k=d_local 0..63 (global co=h*64+k), cols c2 0..63
        for (int p = 0; p < 4; ++p) {
            int g4 = tid + p * 256; int k = g4 >> 4, c4 = g4 & 15;
            uint4 v = *((const uint4*)(WO + ((size_t)ml * 32768 + (size_t)(h * 64 + k) * 64) * 2) + c4);
            unsigned* lp = (unsigned*)&Ws[k * 130 + c4 * 8];
            lp[0] = v.x; lp[1] = v.y; lp[2] = v.z; lp[3] = v.w;
        }
        {   // SA = attn * Vs -> SAs
            float ac[4][8] = {};
            const unsigned* Vu = (const unsigned*)Vs;
            for (int j = 0; j < 64; ++j) {
                float a[4];
                for (int r = 0; r < 4; ++r) a[r] = As[(ty * 4 + r) * 65 + j];
                for (int c = 0; c < 4; ++c) {
                    unsigned u = Vu[j * 65 + tx * 4 + c];
                    float lo = bl(u), hi = bhf(u);
                    for (int r = 0; r < 4; ++r) {
                        ac[r][c * 2] = fmaf(a[r], lo, ac[r][c * 2]);
                        ac[r][c * 2 + 1] = fmaf(a[r], hi, ac[r][c * 2 + 1]);
                    }
                }
            }
            for (int r = 0; r < 4; ++r)
                for (int c = 0; c < 4; ++c)
                    ((unsigned*)SAs)[(ty * 4 + r) * 65 + tx * 4 + c] = pack2(ac[r][c * 2], ac[r][c * 2 + 1]);
        }
        __syncthreads();
        {   // outacc += SAs * WO
            const unsigned* Su = (const unsigned*)SAs;
            const unsigned* Wu = (const unsigned*)Ws;
            for (int k = 0; k < 64; ++k) {
                float xr[4], xi_[4], wr[4], wi[4];
                for (int r = 0; r < 4; ++r) { unsigned u = Su[(ty * 4 + r) * 65 + k]; xr[r] = bl(u); xi_[r] = bhf(u); }
                for (int c = 0; c < 4; ++c) { unsigned u = Wu[k * 65 + tx * 4 + c]; wr[c] = bl(u); wi[c] = bhf(u); }
                for (int r = 0; r < 4; ++r)
                    for (int c = 0; c < 4; ++c) {
                        oar[r][c] = fmaf(xr[r], wr[c], oar[r][c]);
                        oar[r][c] = fmaf(-xi_[r], wi[c], oar[r][c]);
                        oai[r][c] = fmaf(xr[r], wi[c], oai[r][c]);
                        oai[r][c] = fmaf(xi_[r], wr[c], oai[r][c]);
                    }
            }
        }
    }
    for (int r = 0; r < 4; ++r) {
        float4 v0 = {oar[r][0], oai[r][0], oar[r][1], oai[r][1]};
        float4 v1 = {oar[r][2], oai[r][2], oar[r][3], oai[r][3]};
        float4* op = (float4*)(outf + (((size_t)mode * 128 + b * 64 + ty * 4 + r) * 64 + tx * 4) * 2);
        op[0] = v0; op[1] = v1;
    }
}

// ---------- custom irfft2 of padded outf -> out f32 [bs][c2][32][32]
__global__ __launch_bounds__(256) void k_irfft(const float* __restrict__ outf,
                                               float* __restrict__ out) {
    __shared__ float c32[32], s32[32];
    __shared__ float mf[256][18];    // [mode][c2local*2+reim]
    __shared__ float sr[16 * 33], si[16 * 33];
    int tid = threadIdx.x;
    int cg = blockIdx.x;   // 0..7
    int bs = blockIdx.y;   // 0..127
    if (tid < 32) { float s, c; __sincosf(TWO_PI * tid / 32.0f, &s, &c); c32[tid] = c; s32[tid] = s; }
    {
        const float4* gp = (const float4*)(outf + (((size_t)tid * 128 + bs) * 64 + cg * 8) * 2);
        for (int q = 0; q < 4; ++q) {
            float4 v = gp[q];
            mf[tid][q * 4 + 0] = v.x; mf[tid][q * 4 + 1] = v.y;
            mf[tid][q * 4 + 2] = v.z; mf[tid][q * 4 + 3] = v.w;
        }
    }
    __syncthreads();
    for (int cc = 0; cc < 8; ++cc) {
        for (int p = 0; p < 2; ++p) {   // stage1: s'[u][y] = 0.5*f[u][0] + sum_{v>=1} f * e^{+i2pi vy/32}
            int e = tid + p * 256;
            int u = e >> 5, y = e & 31;
            float fr0 = mf[u * 16][cc * 2];
            float fi0 = (u == 0) ? 0.f : mf[u * 16][cc * 2 + 1];
            float ssr = 0.5f * fr0, ssi = 0.5f * fi0;
            for (int v = 1; v < 16; ++v) {
                float fr = mf[u * 16 + v][cc * 2], fi = mf[u * 16 + v][cc * 2 + 1];
                int ph = (v * y) & 31;
                float c = c32[ph], s = s32[ph];
                ssr += fr * c - fi * s;
                ssi += fr * s + fi * c;
            }
            sr[u * 33 + y] = ssr; si[u * 33 + y] = ssi;
        }
        __syncthreads();
        float res[4];
        for (int p = 0; p < 4; ++p) {   // stage2: out = (1/512) sum_u Re{s' e^{+i2pi ux/32}}
            int pos = tid + p * 256;
            int x = pos >> 5, y = pos & 31;
            float acc = 0.f;
            for (int u = 0; u < 16; ++u) {
                int ph = (u * x) & 31;
                acc += sr[u * 33 + y] * c32[ph] - si[u * 33 + y] * s32[ph];
            }
            res[p] = acc * (1.0f / 512.0f);
        }
        float* op = out + ((size_t)(bs * 64 + cg * 8 + cc)) * 1024;
        for (int p = 0; p < 4; ++p) op[tid + p * 256] = res[p];
        __syncthreads();
    }
}

extern "C" void kernel_launch(void* const* d_in, const int* in_sizes, int n_in,
                              void* d_out, int out_size, void* d_ws, size_t ws_size,
                              hipStream_t stream) {
    (void)in_sizes; (void)n_in; (void)out_size;
    const float* seq = (const float*)d_in[0];
    const float* wq = (const float*)d_in[1];
    const float* wk = (const float*)d_in[2];
    const float* wv = (const float*)d_in[3];
    const float* wo = (const float*)d_in[4];
    const float* cw1 = (const float*)d_in[5];
    const float* cb1 = (const float*)d_in[6];
    const float* cw2 = (const float*)d_in[7];
    float* out = (float*)d_out;
    char* ws = (char*)d_ws;
    if (ws_size < WS_TOTAL) return;

    unsigned short* XM = (unsigned short*)(ws + OFF_XM);
    unsigned short* WTA = (unsigned short*)(ws + OFF_WTA);
    unsigned short* WTB = (unsigned short*)(ws + OFF_WTB);
    float* PART = (float*)(ws + OFF_PO);
    float* OUTF = (float*)(ws + OFF_PO);
    float* ATTN = (float*)(ws + OFF_ATTN);

    k_rfft<<<dim3(8, 128), dim3(256), 0, stream>>>(seq, XM);

    // phase 1: per chunk, transpose WQ/WK then fused Q/K + partial scores
    for (int c = 0; c < NCH; ++c) {
        int m0 = c * CH;
        k_transpose<<<dim3(512, CH / 16), dim3(256), 0, stream>>>(wq, WTA, m0);
        k_transpose<<<dim3(512, CH / 16), dim3(256), 0, stream>>>(wk, WTB, m0);
        k_qks<<<dim3(CH / 4, NH, 2), dim3(256), 0, stream>>>(XM, WTA, WTB, PART, m0);
    }
    k_softmax<<<dim3(64, 16), dim3(64), 0, stream>>>(PART, cw1, cb1, cw2, ATTN);

    // phase 2: per chunk, transpose WV/WO then fused V -> attn*V -> wo
    for (int c = 0; c < NCH; ++c) {
        int m0 = c * CH;
        k_transpose<<<dim3(512, CH / 16), dim3(256), 0, stream>>>(wv, WTA, m0);
        k_transpose<<<dim3(512, CH / 16), dim3(256), 0, stream>>>(wo, WTB, m0);
        k_savo<<<dim3(CH, 2), dim3(256), 0, stream>>>(XM, WTA, WTB, ATTN, OUTF, m0);
    }
    k_irfft<<<dim3(8, 128), dim3(256), 0, stream>>>(OUTF, out);
}

// Round 5
// 604.431 us; speedup vs baseline: 3.6717x; 1.4473x over previous
//
#include <hip/hip_runtime.h>

#define TWO_PI 6.28318530717958647692f

// dims
#define NH 8
#define CH 128     // modes per chunk
#define NCH 2

// workspace offsets (bytes), total ~56.25 MiB (proven-safe)
#define OFF_XM   0ull                        // bf16 [256][128][128]     8 MiB  (k'=2ci+ri interleaved)
#define OFF_WTA  (OFF_XM + 8388608ull)       // bf16 [128][32768][2]    16 MiB
#define OFF_WTB  (OFF_WTA + 16777216ull)     // bf16 [128][32768][2]    16 MiB
#define OFF_PO   (OFF_WTB + 16777216ull)     // f32: PART [64][16][64][64] / OUTF [256][128][128]  16 MiB (shared)
#define OFF_ATTN (OFF_PO + 16777216ull)      // bf16 [16][64][64] (128 KiB used of 256 KiB slot)
#define WS_TOTAL (OFF_ATTN + 262144ull)

typedef short bf16x8 __attribute__((ext_vector_type(8)));
typedef float f32x4 __attribute__((ext_vector_type(4)));
#define MFMA_B16(a, b, c) __builtin_amdgcn_mfma_f32_16x16x32_bf16(a, b, c, 0, 0, 0)

__device__ __forceinline__ float bl(unsigned u) { return __uint_as_float(u << 16); }
__device__ __forceinline__ float bhf(unsigned u) { return __uint_as_float(u & 0xffff0000u); }
__device__ __forceinline__ unsigned short f2b(float f) {
    unsigned u = __float_as_uint(f);
    return (unsigned short)((u + 0x7fffu + ((u >> 16) & 1u)) >> 16);
}
__device__ __forceinline__ unsigned pack2(float lo, float hi) {
    return (unsigned)f2b(lo) | ((unsigned)f2b(hi) << 16);
}

// ---------- weight transpose + Parseval prescale: in f32 [R=32768][256][2] -> WT bf16 [CH][R] packed u32
// kind 0: Q/K (sqrt2 family), 1: V (1/2 family), 2: none (wo)
__global__ __launch_bounds__(256) void k_transpose(const float* __restrict__ in,
                                                   unsigned short* __restrict__ outp, int m0, int kind) {
    __shared__ unsigned T[16][65];
    int tid = threadIdx.x;
    size_t r0 = (size_t)blockIdx.x * 64;
    int ml0 = blockIdx.y * 16;
    int u = (m0 + ml0) >> 4;      // mode row fixed per block
    const float2* in2 = (const float2*)in;
    #pragma unroll
    for (int p = 0; p < 4; ++p) {
        int f = tid + p * 256;
        int row = f >> 4, mc = f & 15;     // mc = v
        float fac = (kind == 0) ? (mc > 0 ? 1.41421356f : (u > 0 ? 0.70710678f : 1.f))
                  : (kind == 1) ? (mc > 0 ? 1.f : (u > 0 ? 0.5f : 1.f)) : 1.f;
        float2 v = in2[(r0 + row) * 256 + m0 + ml0 + mc];
        T[mc][row] = pack2(v.x * fac, v.y * fac);
    }
    __syncthreads();
    #pragma unroll
    for (int p = 0; p < 4; ++p) {
        int f = tid + p * 256;
        int ml = f >> 6, rl = f & 63;
        ((unsigned*)outp)[(size_t)(ml0 + ml) * 32768 + r0 + rl] = T[ml][rl];
    }
}

// ---------- truncated rfft2 of seq (f32) -> XM bf16 [mode][bs][k'=2ci+ri]
__global__ __launch_bounds__(256) void k_rfft(const float* __restrict__ seq,
                                              unsigned short* __restrict__ XM) {
    __shared__ float c32[32], s32[32];
    __shared__ float fld[32][33];
    __shared__ float tre[512], tim[512];
    __shared__ float obuf[256][18];
    int tid = threadIdx.x;
    int cig = blockIdx.x;   // 0..7
    int bs = blockIdx.y;    // 0..127
    if (tid < 32) { float s, c; __sincosf(TWO_PI * tid / 32.0f, &s, &c); c32[tid] = c; s32[tid] = s; }
    for (int cl = 0; cl < 8; ++cl) {
        int ci = cig * 8 + cl;
        const float2* src = (const float2*)(seq + ((size_t)bs * 64 + ci) * 1024);
        for (int p = 0; p < 2; ++p) {
            int idx2 = tid + p * 256;
            float2 v = src[idx2];
            int x = idx2 >> 4, y2 = (idx2 & 15) * 2;
            fld[x][y2] = v.x; fld[x][y2 + 1] = v.y;
        }
        __syncthreads();
        for (int p = 0; p < 2; ++p) {
            int e = tid + p * 256;
            int x = e >> 4, v = e & 15;
            float sr = 0.f, si = 0.f;
            for (int y = 0; y < 32; ++y) {
                float f = fld[x][y];
                int ph = (v * y) & 31;
                sr = fmaf(f, c32[ph], sr);
                si = fmaf(-f, s32[ph], si);
            }
            tre[x * 16 + v] = sr; tim[x * 16 + v] = si;
        }
        __syncthreads();
        {
            int u = tid >> 4, v = tid & 15;
            float xr = 0.f, xi = 0.f;
            for (int x = 0; x < 32; ++x) {
                float tr = tre[x * 16 + v], ti = tim[x * 16 + v];
                int ph = (u * x) & 31;
                float c = c32[ph], s = s32[ph];
                xr += tr * c + ti * s;
                xi += ti * c - tr * s;
            }
            obuf[tid][cl * 2] = xr; obuf[tid][cl * 2 + 1] = xi;
        }
        __syncthreads();
    }
    uint4 a, b;
    a.x = pack2(obuf[tid][0], obuf[tid][1]);
    a.y = pack2(obuf[tid][2], obuf[tid][3]);
    a.z = pack2(obuf[tid][4], obuf[tid][5]);
    a.w = pack2(obuf[tid][6], obuf[tid][7]);
    b.x = pack2(obuf[tid][8], obuf[tid][9]);
    b.y = pack2(obuf[tid][10], obuf[tid][11]);
    b.z = pack2(obuf[tid][12], obuf[tid][13]);
    b.w = pack2(obuf[tid][14], obuf[tid][15]);
    uint4* op = (uint4*)(XM + (((size_t)tid * 128 + bs) * 64 + cig * 8) * 2);
    op[0] = a; op[1] = b;
}

// ---------- stage doubled-interleaved complex weight tile into LDS:
// W'[n=2col+ri][k'=2ci+ri'] rows even=(Wr,-Wi), odd=(Wi,Wr); dc zeroes odd rows.
__device__ __forceinline__ void stage_w(unsigned char* ws, const unsigned* __restrict__ src,
                                        int stride, bool dc, int tid) {
    #pragma unroll
    for (int p = 0; p < 16; ++p) {
        int g = tid + p * 256;
        int col = (g & 15) | (((g >> 6) & 3) << 4);
        int ci  = ((g >> 4) & 3) | ((g >> 8) << 2);
        unsigned uu = src[ci * stride + col];
        float wr_ = bl(uu), wi_ = bhf(uu);
        int r0 = col * 2;
        *(unsigned*)(ws + r0 * 256 + ((ci * 4) ^ ((r0 & 7) << 4))) = pack2(wr_, -wi_);
        *(unsigned*)(ws + (r0 + 1) * 256 + ((ci * 4) ^ (((r0 + 1) & 7) << 4))) = dc ? 0u : pack2(wi_, wr_);
    }
}

// ---------- fused MFMA Q/K modemix + scores: block=(mg of 4 modes, h, b)
__global__ __launch_bounds__(256) void k_qks(const unsigned short* __restrict__ XM,
                                             const unsigned* __restrict__ WQ,
                                             const unsigned* __restrict__ WK,
                                             float* __restrict__ part, int mbase) {
    __shared__ __align__(16) unsigned char Xs[16384];
    __shared__ __align__(16) unsigned char Ws[32768];
    __shared__ __align__(16) unsigned char Qs[16384];
    __shared__ __align__(16) unsigned char Ks[16384];
    int tid = threadIdx.x;
    int mg = blockIdx.x, h = blockIdx.y, b = blockIdx.z;
    int lane = tid & 63, w = tid >> 6;
    int lr = lane & 15, lg = lane >> 4;
    int wr = w & 1, wc = w >> 1;
    int sxa = (lr & 7) << 4;
    f32x4 zf = {0.f, 0.f, 0.f, 0.f};
    f32x4 sacc[2][2];
    sacc[0][0] = zf; sacc[0][1] = zf; sacc[1][0] = zf; sacc[1][1] = zf;
    for (int mm = 0; mm < 4; ++mm) {
        int ml = mg * 4 + mm;
        int mode = mbase + ml;
        bool dc = (mode == 0);
        __syncthreads();
        {   // stage Xs [64 tok][128 k'] swizzled
            const unsigned short* xg = XM + ((size_t)mode * 128 + b * 64) * 128;
            #pragma unroll
            for (int p = 0; p < 4; ++p) {
                int g = tid + p * 256; int row = g >> 4, c16 = g & 15;
                uint4 v = *(const uint4*)(xg + row * 128 + c16 * 8);
                *(uint4*)(Xs + row * 256 + ((c16 * 16) ^ ((row & 7) << 4))) = v;
            }
        }
        stage_w(Ws, WQ + (size_t)ml * 32768 + h * 64, 512, dc, tid);
        __syncthreads();
        {   // Qt = Xs * WQ'
            f32x4 acc[2][4];
            #pragma unroll
            for (int m = 0; m < 2; ++m)
                #pragma unroll
                for (int n = 0; n < 4; ++n) acc[m][n] = zf;
            #pragma unroll
            for (int ks = 0; ks < 4; ++ks) {
                int kb = (ks * 64 + lg * 16) ^ sxa;
                bf16x8 a0 = *(const bf16x8*)(Xs + (wr * 32 + lr) * 256 + kb);
                bf16x8 a1 = *(const bf16x8*)(Xs + (wr * 32 + 16 + lr) * 256 + kb);
                #pragma unroll
                for (int n = 0; n < 4; ++n) {
                    bf16x8 bb = *(const bf16x8*)(Ws + (wc * 64 + n * 16 + lr) * 256 + kb);
                    acc[0][n] = MFMA_B16(a0, bb, acc[0][n]);
                    acc[1][n] = MFMA_B16(a1, bb, acc[1][n]);
                }
            }
            #pragma unroll
            for (int m = 0; m < 2; ++m)
                #pragma unroll
                for (int n = 0; n < 4; ++n) {
                    int colb = (wc * 64 + n * 16 + lr) * 2;
                    #pragma unroll
                    for (int r = 0; r < 4; ++r) {
                        int row = wr * 32 + m * 16 + lg * 4 + r;
                        *(unsigned short*)(Qs + row * 256 + (colb ^ ((row & 7) << 4))) = f2b(acc[m][n][r]);
                    }
                }
        }
        __syncthreads();
        stage_w(Ws, WK + (size_t)ml * 32768 + h * 64, 512, dc, tid);
        __syncthreads();
        {   // Kt = Xs * WK'
            f32x4 acc[2][4];
            #pragma unroll
            for (int m = 0; m < 2; ++m)
                #pragma unroll
                for (int n = 0; n < 4; ++n) acc[m][n] = zf;
            #pragma unroll
            for (int ks = 0; ks < 4; ++ks) {
                int kb = (ks * 64 + lg * 16) ^ sxa;
                bf16x8 a0 = *(const bf16x8*)(Xs + (wr * 32 + lr) * 256 + kb);
                bf16x8 a1 = *(const bf16x8*)(Xs + (wr * 32 + 16 + lr) * 256 + kb);
                #pragma unroll
                for (int n = 0; n < 4; ++n) {
                    bf16x8 bb = *(const bf16x8*)(Ws + (wc * 64 + n * 16 + lr) * 256 + kb);
                    acc[0][n] = MFMA_B16(a0, bb, acc[0][n]);
                    acc[1][n] = MFMA_B16(a1, bb, acc[1][n]);
                }
            }
            #pragma unroll
            for (int m = 0; m < 2; ++m)
                #pragma unroll
                for (int n = 0; n < 4; ++n) {
                    int colb = (wc * 64 + n * 16 + lr) * 2;
                    #pragma unroll
                    for (int r = 0; r < 4; ++r) {
                        int row = wr * 32 + m * 16 + lg * 4 + r;
                        *(unsigned short*)(Ks + row * 256 + (colb ^ ((row & 7) << 4))) = f2b(acc[m][n][r]);
                    }
                }
        }
        __syncthreads();
        {   // scores: sacc += Qt(64x128) . Kt(64x128)^T over k'=c'
            #pragma unroll
            for (int ks = 0; ks < 4; ++ks) {
                int kb = (ks * 64 + lg * 16) ^ sxa;
                bf16x8 a0 = *(const bf16x8*)(Qs + (wr * 32 + lr) * 256 + kb);
                bf16x8 a1 = *(const bf16x8*)(Qs + (wr * 32 + 16 + lr) * 256 + kb);
                bf16x8 b0 = *(const bf16x8*)(Ks + (wc * 32 + lr) * 256 + kb);
                bf16x8 b1 = *(const bf16x8*)(Ks + (wc * 32 + 16 + lr) * 256 + kb);
                sacc[0][0] = MFMA_B16(a0, b0, sacc[0][0]);
                sacc[0][1] = MFMA_B16(a0, b1, sacc[0][1]);
                sacc[1][0] = MFMA_B16(a1, b0, sacc[1][0]);
                sacc[1][1] = MFMA_B16(a1, b1, sacc[1][1]);
            }
        }
    }
    float* pp = part + (((size_t)((mbase >> 2) + mg) * 16 + b * 8 + h) << 12);
    #pragma unroll
    for (int m = 0; m < 2; ++m)
        #pragma unroll
        for (int n = 0; n < 2; ++n)
            #pragma unroll
            for (int r = 0; r < 4; ++r)
                pp[(wr * 32 + m * 16 + lg * 4 + r) * 64 + wc * 32 + n * 16 + lr] = sacc[m][n][r];
}

// ---------- reduce partials + inline CPB bias + softmax -> attn bf16
__global__ void k_softmax(const float* __restrict__ part,
                          const float* __restrict__ w1, const float* __restrict__ b1,
                          const float* __restrict__ w2, unsigned short* __restrict__ attnb) {
    int j = threadIdx.x;   // 64
    int i = blockIdx.x;    // 64
    int bh = blockIdx.y;   // 16
    int h = bh & 7;
    float s = 0.f;
    for (int mg = 0; mg < 64; ++mg)
        s += part[(((size_t)mg * 16 + bh) * 64 + i) * 64 + j];
    float dx = (float)((i >> 3) - (j >> 3));
    float dy = (float)((i & 7) - (j & 7));
    float rx = (dx > 0.f ? 1.f : (dx < 0.f ? -1.f : 0.f)) * log1pf(fabsf(dx));
    float ry = (dy > 0.f ? 1.f : (dy < 0.f ? -1.f : 0.f)) * log1pf(fabsf(dy));
    float bias = 0.f;
    for (int l = 0; l < 64; ++l) {
        float hv = fmaxf(rx * w1[l] + ry * w1[64 + l] + b1[l], 0.f);
        bias = fmaf(hv, w2[l * NH + h], bias);
    }
    s = s * (1.0f / 262144.0f) + bias;
    float m = s;
    for (int o = 32; o >= 1; o >>= 1) m = fmaxf(m, __shfl_xor(m, o));
    float e = expf(s - m);
    float t = e;
    for (int o = 32; o >= 1; o >>= 1) t += __shfl_xor(t, o);
    attnb[((size_t)bh * 64 + i) * 64 + j] = f2b(e / t);
}

// ---------- fused MFMA V modemix + attn*V + wo: block=(mode_local, b)
__global__ __launch_bounds__(256) void k_savo(const unsigned short* __restrict__ XM,
                                              const unsigned* __restrict__ WV,
                                              const unsigned* __restrict__ WO,
                                              const unsigned short* __restrict__ attnb,
                                              float* __restrict__ outf, int mbase) {
    __shared__ __align__(16) unsigned char Xs[16384];
    __shared__ __align__(16) unsigned char Ws[32768];
    __shared__ __align__(16) unsigned char Vt[16384];   // [128 c'][64 j] bf16 (transposed Vtilde)
    __shared__ __align__(16) unsigned char Ss[16384];   // [64 i][128 c'] bf16
    int tid = threadIdx.x;
    int ml = blockIdx.x, b = blockIdx.y;
    int mode = mbase + ml;
    bool dc = (mode == 0);
    int lane = tid & 63, w = tid >> 6;
    int lr = lane & 15, lg = lane >> 4;
    int wr = w & 1, wc = w >> 1;
    int sxa = (lr & 7) << 4;
    f32x4 zf = {0.f, 0.f, 0.f, 0.f};
    {   // stage Xs once
        const unsigned short* xg = XM + ((size_t)mode * 128 + b * 64) * 128;
        #pragma unroll
        for (int p = 0; p < 4; ++p) {
            int g = tid + p * 256; int row = g >> 4, c16 = g & 15;
            uint4 v = *(const uint4*)(xg + row * 128 + c16 * 8);
            *(uint4*)(Xs + row * 256 + ((c16 * 16) ^ ((row & 7) << 4))) = v;
        }
    }
    f32x4 oacc[2][4];
    #pragma unroll
    for (int m = 0; m < 2; ++m)
        #pragma unroll
        for (int n = 0; n < 4; ++n) oacc[m][n] = zf;
    for (int h = 0; h < NH; ++h) {
        __syncthreads();
        stage_w(Ws, WV + (size_t)ml * 32768 + h * 64, 512, dc, tid);
        bf16x8 af[2][2];
        #pragma unroll
        for (int m = 0; m < 2; ++m)
            #pragma unroll
            for (int ks = 0; ks < 2; ++ks) {
                int irow = wr * 32 + m * 16 + lr;
                af[m][ks] = *(const bf16x8*)(attnb + (((size_t)(b * 8 + h) * 64 + irow) * 64 + ks * 32 + lg * 8));
            }
        __syncthreads();
        {   // Vtilde = Xs * WV' -> Vt transposed
            f32x4 vacc[2][4];
            #pragma unroll
            for (int m = 0; m < 2; ++m)
                #pragma unroll
                for (int n = 0; n < 4; ++n) vacc[m][n] = zf;
            #pragma unroll
            for (int ks = 0; ks < 4; ++ks) {
                int kb = (ks * 64 + lg * 16) ^ sxa;
                bf16x8 a0 = *(const bf16x8*)(Xs + (wr * 32 + lr) * 256 + kb);
                bf16x8 a1 = *(const bf16x8*)(Xs + (wr * 32 + 16 + lr) * 256 + kb);
                #pragma unroll
                for (int n = 0; n < 4; ++n) {
                    bf16x8 bb = *(const bf16x8*)(Ws + (wc * 64 + n * 16 + lr) * 256 + kb);
                    vacc[0][n] = MFMA_B16(a0, bb, vacc[0][n]);
                    vacc[1][n] = MFMA_B16(a1, bb, vacc[1][n]);
                }
            }
            #pragma unroll
            for (int m = 0; m < 2; ++m)
                #pragma unroll
                for (int n = 0; n < 4; ++n) {
                    int cp = wc * 64 + n * 16 + lr;
                    int j0 = wr * 32 + m * 16 + lg * 4;
                    uint2 t;
                    t.x = pack2(vacc[m][n][0], vacc[m][n][1]);
                    t.y = pack2(vacc[m][n][2], vacc[m][n][3]);
                    *(uint2*)(Vt + cp * 128 + ((j0 * 2) ^ ((cp & 7) << 4))) = t;
                }
        }
        __syncthreads();
        stage_w(Ws, WO + (size_t)ml * 32768 + h * 4096, 64, false, tid);
        {   // SA = attn * Vtilde  (A=attn regs, B=Vt)
            f32x4 sa_[2][4];
            #pragma unroll
            for (int m = 0; m < 2; ++m)
                #pragma unroll
                for (int n = 0; n < 4; ++n) sa_[m][n] = zf;
            #pragma unroll
            for (int ks = 0; ks < 2; ++ks) {
                int kb = (ks * 64 + lg * 16) ^ sxa;
                #pragma unroll
                for (int n = 0; n < 4; ++n) {
                    bf16x8 bb = *(const bf16x8*)(Vt + (wc * 64 + n * 16 + lr) * 128 + kb);
                    sa_[0][n] = MFMA_B16(af[0][ks], bb, sa_[0][n]);
                    sa_[1][n] = MFMA_B16(af[1][ks], bb, sa_[1][n]);
                }
            }
            #pragma unroll
            for (int m = 0; m < 2; ++m)
                #pragma unroll
                for (int n = 0; n < 4; ++n) {
                    int colb = (wc * 64 + n * 16 + lr) * 2;
                    #pragma unroll
                    for (int r = 0; r < 4; ++r) {
                        int row = wr * 32 + m * 16 + lg * 4 + r;
                        *(unsigned short*)(Ss + row * 256 + (colb ^ ((row & 7) << 4))) = f2b(sa_[m][n][r]);
                    }
                }
        }
        __syncthreads();
        {   // OUT += SA * WO'
            #pragma unroll
            for (int ks = 0; ks < 4; ++ks) {
                int kb = (ks * 64 + lg * 16) ^ sxa;
                bf16x8 a0 = *(const bf16x8*)(Ss + (wr * 32 + lr) * 256 + kb);
                bf16x8 a1 = *(const bf16x8*)(Ss + (wr * 32 + 16 + lr) * 256 + kb);
                #pragma unroll
                for (int n = 0; n < 4; ++n) {
                    bf16x8 bb = *(const bf16x8*)(Ws + (wc * 64 + n * 16 + lr) * 256 + kb);
                    oacc[0][n] = MFMA_B16(a0, bb, oacc[0][n]);
                    oacc[1][n] = MFMA_B16(a1, bb, oacc[1][n]);
                }
            }
        }
    }
    #pragma unroll
    for (int m = 0; m < 2; ++m)
        #pragma unroll
        for (int n = 0; n < 4; ++n)
            #pragma unroll
            for (int r = 0; r < 4; ++r) {
                int i = wr * 32 + m * 16 + lg * 4 + r;
                int c2p = wc * 64 + n * 16 + lr;
                outf[((size_t)mode * 128 + b * 64 + i) * 128 + c2p] = oacc[m][n][r];
            }
}

// ---------- custom irfft2 of padded outf -> out f32 [bs][c2][32][32]
__global__ __launch_bounds__(256) void k_irfft(const float* __restrict__ outf,
                                               float* __restrict__ out) {
    __shared__ float c32[32], s32[32];
    __shared__ float mf[256][18];
    __shared__ float sr[16 * 33], si[16 * 33];
    int tid = threadIdx.x;
    int cg = blockIdx.x;   // 0..7
    int bs = blockIdx.y;   // 0..127
    if (tid < 32) { float s, c; __sincosf(TWO_PI * tid / 32.0f, &s, &c); c32[tid] = c; s32[tid] = s; }
    {
        const float4* gp = (const float4*)(outf + (((size_t)tid * 128 + bs) * 64 + cg * 8) * 2);
        for (int q = 0; q < 4; ++q) {
            float4 v = gp[q];
            mf[tid][q * 4 + 0] = v.x; mf[tid][q * 4 + 1] = v.y;
            mf[tid][q * 4 + 2] = v.z; mf[tid][q * 4 + 3] = v.w;
        }
    }
    __syncthreads();
    for (int cc = 0; cc < 8; ++cc) {
        for (int p = 0; p < 2; ++p) {
            int e = tid + p * 256;
            int u = e >> 5, y = e & 31;
            float fr0 = mf[u * 16][cc * 2];
            float fi0 = (u == 0) ? 0.f : mf[u * 16][cc * 2 + 1];
            float ssr = 0.5f * fr0, ssi = 0.5f * fi0;
            for (int v = 1; v < 16; ++v) {
                float fr = mf[u * 16 + v][cc * 2], fi = mf[u * 16 + v][cc * 2 + 1];
                int ph = (v * y) & 31;
                float c = c32[ph], s = s32[ph];
                ssr += fr * c - fi * s;
                ssi += fr * s + fi * c;
            }
            sr[u * 33 + y] = ssr; si[u * 33 + y] = ssi;
        }
        __syncthreads();
        float res[4];
        for (int p = 0; p < 4; ++p) {
            int pos = tid + p * 256;
            int x = pos >> 5, y = pos & 31;
            float acc = 0.f;
            for (int u = 0; u < 16; ++u) {
                int ph = (u * x) & 31;
                acc += sr[u * 33 + y] * c32[ph] - si[u * 33 + y] * s32[ph];
            }
            res[p] = acc * (1.0f / 512.0f);
        }
        float* op = out + ((size_t)(bs * 64 + cg * 8 + cc)) * 1024;
        for (int p = 0; p < 4; ++p) op[tid + p * 256] = res[p];
        __syncthreads();
    }
}

extern "C" void kernel_launch(void* const* d_in, const int* in_sizes, int n_in,
                              void* d_out, int out_size, void* d_ws, size_t ws_size,
                              hipStream_t stream) {
    (void)in_sizes; (void)n_in; (void)out_size;
    const float* seq = (const float*)d_in[0];
    const float* wq = (const float*)d_in[1];
    const float* wk = (const float*)d_in[2];
    const float* wv = (const float*)d_in[3];
    const float* wo = (const float*)d_in[4];
    const float* cw1 = (const float*)d_in[5];
    const float* cb1 = (const float*)d_in[6];
    const float* cw2 = (const float*)d_in[7];
    float* out = (float*)d_out;
    char* ws = (char*)d_ws;
    if (ws_size < WS_TOTAL) return;

    unsigned short* XM = (unsigned short*)(ws + OFF_XM);
    unsigned short* WTA = (unsigned short*)(ws + OFF_WTA);
    unsigned short* WTB = (unsigned short*)(ws + OFF_WTB);
    float* PART = (float*)(ws + OFF_PO);
    float* OUTF = (float*)(ws + OFF_PO);
    unsigned short* ATTNB = (unsigned short*)(ws + OFF_ATTN);

    k_rfft<<<dim3(8, 128), dim3(256), 0, stream>>>(seq, XM);

    for (int c = 0; c < NCH; ++c) {
        int m0 = c * CH;
        k_transpose<<<dim3(512, CH / 16), dim3(256), 0, stream>>>(wq, WTA, m0, 0);
        k_transpose<<<dim3(512, CH / 16), dim3(256), 0, stream>>>(wk, WTB, m0, 0);
        k_qks<<<dim3(CH / 4, NH, 2), dim3(256), 0, stream>>>(XM, (const unsigned*)WTA, (const unsigned*)WTB, PART, m0);
    }
    k_softmax<<<dim3(64, 16), dim3(64), 0, stream>>>(PART, cw1, cb1, cw2, ATTNB);

    for (int c = 0; c < NCH; ++c) {
        int m0 = c * CH;
        k_transpose<<<dim3(512, CH / 16), dim3(256), 0, stream>>>(wv, WTA, m0, 1);
        k_transpose<<<dim3(512, CH / 16), dim3(256), 0, stream>>>(wo, WTB, m0, 2);
        k_savo<<<dim3(CH, 2), dim3(256), 0, stream>>>(XM, (const unsigned*)WTA, (const unsigned*)WTB, ATTNB, OUTF, m0);
    }
    k_irfft<<<dim3(8, 128), dim3(256), 0, stream>>>(OUTF, out);
}

// Round 7
// 389.223 us; speedup vs baseline: 5.7019x; 1.5529x over previous
//
#include <hip/hip_runtime.h>

#define TWO_PI 6.28318530717958647692f

// dims
#define NH 8
#define CH 128     // modes per chunk
#define NCH 2

// workspace offsets (bytes), total ~56.25 MiB (proven-safe)
#define OFF_XM   0ull                        // bf16 [256][128][128]     8 MiB  (k'=2ci+ri interleaved)
#define OFF_WTA  (OFF_XM + 8388608ull)       // u32 tiles [CH][8][64][64] 16 MiB
#define OFF_WTB  (OFF_WTA + 16777216ull)     // u32 tiles [CH][8][64][64] 16 MiB
#define OFF_PO   (OFF_WTB + 16777216ull)     // f32: PART [64][16][64][64] / OUTF [256][128][128]  16 MiB (shared)
#define OFF_ATTN (OFF_PO + 16777216ull)      // bf16 [16][64][64]
#define WS_TOTAL (OFF_ATTN + 262144ull)

typedef short bf16x8 __attribute__((ext_vector_type(8)));
typedef float f32x4 __attribute__((ext_vector_type(4)));
#define MFMA_B16(a, b, c) __builtin_amdgcn_mfma_f32_16x16x32_bf16(a, b, c, 0, 0, 0)

__device__ __forceinline__ float bl(unsigned u) { return __uint_as_float(u << 16); }
__device__ __forceinline__ unsigned short f2b(float f) {
    unsigned u = __float_as_uint(f);
    return (unsigned short)((u + 0x7fffu + ((u >> 16) & 1u)) >> 16);
}
__device__ __forceinline__ unsigned pack2(float lo, float hi) {
    return (unsigned)f2b(lo) | ((unsigned)f2b(hi) << 16);
}

// Build doubled-interleaved B-fragment from complex u32 tile Wt[ci][co^ci] (pitch 64).
// Row n = n0+lr: ri=n&1, co=n>>1. even: (Wr,-Wi); odd: (Wi,Wr); dc zeroes odd rows.
__device__ __forceinline__ bf16x8 mkfrag(const unsigned* __restrict__ Wt, int co_l, int ri,
                                         int ci0, bool dc) {
    unsigned a0 = Wt[(ci0 + 0) * 64 + (co_l ^ (ci0 + 0))];
    unsigned a1 = Wt[(ci0 + 1) * 64 + (co_l ^ (ci0 + 1))];
    unsigned a2 = Wt[(ci0 + 2) * 64 + (co_l ^ (ci0 + 2))];
    unsigned a3 = Wt[(ci0 + 3) * 64 + (co_l ^ (ci0 + 3))];
    uint4 r;
    if (ri) {
        if (dc) { r.x = 0u; r.y = 0u; r.z = 0u; r.w = 0u; }
        else {
            r.x = (a0 >> 16) | (a0 << 16); r.y = (a1 >> 16) | (a1 << 16);
            r.z = (a2 >> 16) | (a2 << 16); r.w = (a3 >> 16) | (a3 << 16);
        }
    } else {
        r.x = a0 ^ 0x80000000u; r.y = a1 ^ 0x80000000u;
        r.z = a2 ^ 0x80000000u; r.w = a3 ^ 0x80000000u;
    }
    return __builtin_bit_cast(bf16x8, r);
}

// ---------- weight transpose + Parseval prescale: f32 [R=32768][256][2] -> u32 tiles [ml][h][ci][co]
// kind 0: Q/K (sqrt2, layout ci*512+h*64+co), 1: V (1/2, same layout), 2: wo (none, layout h*4096+ci*64+co)
__global__ __launch_bounds__(256) void k_transpose2(const float* __restrict__ srcA, unsigned* __restrict__ dstA, int kindA,
                                                    const float* __restrict__ srcB, unsigned* __restrict__ dstB, int kindB,
                                                    int m0) {
    const float* in = (blockIdx.z == 0) ? srcA : srcB;
    unsigned* outp = (blockIdx.z == 0) ? dstA : dstB;
    int kind = (blockIdx.z == 0) ? kindA : kindB;
    __shared__ unsigned T[16][65];
    int tid = threadIdx.x;
    int r0 = blockIdx.x * 64;
    int ci, h;
    if (kind == 2) { h = r0 >> 12; ci = (r0 >> 6) & 63; }   // wo: r = h*4096 + ci*64 + co
    else           { ci = r0 >> 9; h = (r0 >> 6) & 7; }     // wq/wk/wv: r = ci*512 + h*64 + co
    int ml0 = blockIdx.y * 16;
    int u = (m0 + ml0) >> 4;
    const float2* in2 = (const float2*)in;
    #pragma unroll
    for (int p = 0; p < 4; ++p) {
        int f = tid + p * 256;
        int row = f >> 4, mc = f & 15;     // mc = v (mode col within 16-group)
        float fac = (kind == 0) ? (mc > 0 ? 1.41421356f : (u > 0 ? 0.70710678f : 1.f))
                  : (kind == 1) ? (mc > 0 ? 1.f : (u > 0 ? 0.5f : 1.f)) : 1.f;
        float2 v = in2[(size_t)(r0 + row) * 256 + m0 + ml0 + mc];
        T[mc][row] = pack2(v.x * fac, v.y * fac);
    }
    __syncthreads();
    #pragma unroll
    for (int p = 0; p < 4; ++p) {
        int f = tid + p * 256;
        int ml = f >> 6, co = f & 63;
        outp[((size_t)((ml0 + ml) * 8 + h) << 12) + ci * 64 + co] = T[ml][co];
    }
}

// ---------- truncated rfft2 of seq (f32) -> XM bf16 [mode][bs][k'=2ci+ri]
__global__ __launch_bounds__(256) void k_rfft(const float* __restrict__ seq,
                                              unsigned short* __restrict__ XM) {
    __shared__ float c32[32], s32[32];
    __shared__ float fld[32][33];
    __shared__ float tre[512], tim[512];
    __shared__ float obuf[256][18];
    int tid = threadIdx.x;
    int cig = blockIdx.x;   // 0..7
    int bs = blockIdx.y;    // 0..127
    if (tid < 32) { float s, c; __sincosf(TWO_PI * tid / 32.0f, &s, &c); c32[tid] = c; s32[tid] = s; }
    for (int cl = 0; cl < 8; ++cl) {
        int ci = cig * 8 + cl;
        const float2* src = (const float2*)(seq + ((size_t)bs * 64 + ci) * 1024);
        for (int p = 0; p < 2; ++p) {
            int idx2 = tid + p * 256;
            float2 v = src[idx2];
            int x = idx2 >> 4, y2 = (idx2 & 15) * 2;
            fld[x][y2] = v.x; fld[x][y2 + 1] = v.y;
        }
        __syncthreads();
        for (int p = 0; p < 2; ++p) {
            int e = tid + p * 256;
            int x = e >> 4, v = e & 15;
            float sr = 0.f, si = 0.f;
            for (int y = 0; y < 32; ++y) {
                float f = fld[x][y];
                int ph = (v * y) & 31;
                sr = fmaf(f, c32[ph], sr);
                si = fmaf(-f, s32[ph], si);
            }
            tre[x * 16 + v] = sr; tim[x * 16 + v] = si;
        }
        __syncthreads();
        {
            int u = tid >> 4, v = tid & 15;
            float xr = 0.f, xi = 0.f;
            for (int x = 0; x < 32; ++x) {
                float tr = tre[x * 16 + v], ti = tim[x * 16 + v];
                int ph = (u * x) & 31;
                float c = c32[ph], s = s32[ph];
                xr += tr * c + ti * s;
                xi += ti * c - tr * s;
            }
            obuf[tid][cl * 2] = xr; obuf[tid][cl * 2 + 1] = xi;
        }
        __syncthreads();
    }
    uint4 a, b;
    a.x = pack2(obuf[tid][0], obuf[tid][1]);
    a.y = pack2(obuf[tid][2], obuf[tid][3]);
    a.z = pack2(obuf[tid][4], obuf[tid][5]);
    a.w = pack2(obuf[tid][6], obuf[tid][7]);
    b.x = pack2(obuf[tid][8], obuf[tid][9]);
    b.y = pack2(obuf[tid][10], obuf[tid][11]);
    b.z = pack2(obuf[tid][12], obuf[tid][13]);
    b.w = pack2(obuf[tid][14], obuf[tid][15]);
    uint4* op = (uint4*)(XM + (((size_t)tid * 128 + bs) * 64 + cig * 8) * 2);
    op[0] = a; op[1] = b;
}

// ---------- fused MFMA Q/K modemix + scores: 512 threads, block=(mg of 4 modes, h, b)
__global__ __launch_bounds__(512) void k_qks(const unsigned short* __restrict__ XM,
                                             const unsigned* __restrict__ WQ,
                                             const unsigned* __restrict__ WK,
                                             float* __restrict__ part, int mbase) {
    __shared__ __align__(16) unsigned char Xs[16384];
    __shared__ __align__(16) unsigned Wq[4096];
    __shared__ __align__(16) unsigned Wk[4096];
    __shared__ __align__(16) unsigned char Qs[16384];
    __shared__ __align__(16) unsigned char Ks[16384];
    int tid = threadIdx.x;
    int mg = blockIdx.x, h = blockIdx.y, b = blockIdx.z;
    int lane = tid & 63, w = tid >> 6;
    int lr = lane & 15, lg = lane >> 4;
    int wr = w & 1, wc = w >> 1;          // wr 0..1, wc 0..3
    int sxa = (lr & 7) << 4;
    int ri = lr & 1;
    f32x4 zf = {0.f, 0.f, 0.f, 0.f};
    f32x4 sacc[2];
    sacc[0] = zf; sacc[1] = zf;
    for (int mm = 0; mm < 4; ++mm) {
        int ml = mg * 4 + mm;
        int mode = mbase + ml;
        bool dc = (mode == 0);
        __syncthreads();
        {   // stage Xs [64 tok][128 k'] swizzled
            const unsigned short* xg = XM + ((size_t)mode * 128 + b * 64) * 128;
            #pragma unroll
            for (int p = 0; p < 2; ++p) {
                int g = tid + p * 512; int row = g >> 4, c16 = g & 15;
                uint4 v = *(const uint4*)(xg + row * 128 + c16 * 8);
                *(uint4*)(Xs + row * 256 + ((c16 * 16) ^ ((row & 7) << 4))) = v;
            }
        }
        {   // stage Wq + Wk u32 tiles (16KB each, coalesced, swizzled placement co^ci)
            const unsigned* tq = WQ + ((size_t)(ml * 8 + h) << 12);
            const unsigned* tk = WK + ((size_t)(ml * 8 + h) << 12);
            #pragma unroll
            for (int p = 0; p < 16; ++p) {
                int idx = tid + p * 512;
                int r = idx & 4095;
                int ci = r >> 6, co = r & 63;
                if (idx < 4096) Wq[ci * 64 + (co ^ ci)] = tq[r];
                else            Wk[ci * 64 + (co ^ ci)] = tk[r];
            }
        }
        __syncthreads();
        {   // Qt = Xs*WQ' -> Qs ; Kt = Xs*WK' -> Ks
            f32x4 qa[2][2], ka[2][2];
            #pragma unroll
            for (int m = 0; m < 2; ++m)
                #pragma unroll
                for (int n = 0; n < 2; ++n) { qa[m][n] = zf; ka[m][n] = zf; }
            #pragma unroll
            for (int ks = 0; ks < 4; ++ks) {
                int kb = (ks * 64 + lg * 16) ^ sxa;
                int ci0 = ks * 16 + lg * 4;
                bf16x8 a0 = *(const bf16x8*)(Xs + (wr * 32 + lr) * 256 + kb);
                bf16x8 a1 = *(const bf16x8*)(Xs + (wr * 32 + 16 + lr) * 256 + kb);
                #pragma unroll
                for (int n = 0; n < 2; ++n) {
                    int co_l = wc * 16 + n * 8 + (lr >> 1);   // (n0+lr)>>1, n0=wc*32+n*16
                    bf16x8 bq = mkfrag(Wq, co_l, ri, ci0, dc);
                    bf16x8 bk = mkfrag(Wk, co_l, ri, ci0, dc);
                    qa[0][n] = MFMA_B16(a0, bq, qa[0][n]);
                    qa[1][n] = MFMA_B16(a1, bq, qa[1][n]);
                    ka[0][n] = MFMA_B16(a0, bk, ka[0][n]);
                    ka[1][n] = MFMA_B16(a1, bk, ka[1][n]);
                }
            }
            #pragma unroll
            for (int m = 0; m < 2; ++m)
                #pragma unroll
                for (int n = 0; n < 2; ++n) {
                    int colb = (wc * 32 + n * 16 + lr) * 2;
                    #pragma unroll
                    for (int r = 0; r < 4; ++r) {
                        int row = wr * 32 + m * 16 + lg * 4 + r;
                        int swz = (row & 7) << 4;
                        *(unsigned short*)(Qs + row * 256 + (colb ^ swz)) = f2b(qa[m][n][r]);
                        *(unsigned short*)(Ks + row * 256 + (colb ^ swz)) = f2b(ka[m][n][r]);
                    }
                }
        }
        __syncthreads();
        {   // scores: sacc += Qt(64x128) . Kt(64x128)^T
            #pragma unroll
            for (int ks = 0; ks < 4; ++ks) {
                int kb = (ks * 64 + lg * 16) ^ sxa;
                bf16x8 a0 = *(const bf16x8*)(Qs + (wr * 32 + lr) * 256 + kb);
                bf16x8 a1 = *(const bf16x8*)(Qs + (wr * 32 + 16 + lr) * 256 + kb);
                bf16x8 b0 = *(const bf16x8*)(Ks + (wc * 16 + lr) * 256 + kb);
                sacc[0] = MFMA_B16(a0, b0, sacc[0]);
                sacc[1] = MFMA_B16(a1, b0, sacc[1]);
            }
        }
    }
    float* pp = part + (((size_t)((mbase >> 2) + mg) * 16 + b * 8 + h) << 12);
    #pragma unroll
    for (int m = 0; m < 2; ++m)
        #pragma unroll
        for (int r = 0; r < 4; ++r)
            pp[(wr * 32 + m * 16 + lg * 4 + r) * 64 + wc * 16 + lr] = sacc[m][r];
}

// ---------- reduce partials + inline CPB bias + softmax -> attn bf16
__global__ void k_softmax(const float* __restrict__ part,
                          const float* __restrict__ w1, const float* __restrict__ b1,
                          const float* __restrict__ w2, unsigned short* __restrict__ attnb) {
    int j = threadIdx.x;   // 64
    int i = blockIdx.x;    // 64
    int bh = blockIdx.y;   // 16
    int h = bh & 7;
    float s = 0.f;
    for (int mg = 0; mg < 64; ++mg)
        s += part[(((size_t)mg * 16 + bh) * 64 + i) * 64 + j];
    float dx = (float)((i >> 3) - (j >> 3));
    float dy = (float)((i & 7) - (j & 7));
    float rx = (dx > 0.f ? 1.f : (dx < 0.f ? -1.f : 0.f)) * log1pf(fabsf(dx));
    float ry = (dy > 0.f ? 1.f : (dy < 0.f ? -1.f : 0.f)) * log1pf(fabsf(dy));
    float bias = 0.f;
    for (int l = 0; l < 64; ++l) {
        float hv = fmaxf(rx * w1[l] + ry * w1[64 + l] + b1[l], 0.f);
        bias = fmaf(hv, w2[l * NH + h], bias);
    }
    s = s * (1.0f / 262144.0f) + bias;
    float m = s;
    for (int o = 32; o >= 1; o >>= 1) m = fmaxf(m, __shfl_xor(m, o));
    float e = expf(s - m);
    float t = e;
    for (int o = 32; o >= 1; o >>= 1) t += __shfl_xor(t, o);
    attnb[((size_t)bh * 64 + i) * 64 + j] = f2b(e / t);
}

// ---------- fused MFMA V modemix + attn*V + wo: 512 threads, block=(mode_local, b)
__global__ __launch_bounds__(512) void k_savo(const unsigned short* __restrict__ XM,
                                              const unsigned* __restrict__ WV,
                                              const unsigned* __restrict__ WO,
                                              const unsigned short* __restrict__ attnb,
                                              float* __restrict__ outf, int mbase) {
    __shared__ __align__(16) unsigned char Xs[16384];
    __shared__ __align__(16) unsigned Wv[4096];
    __shared__ __align__(16) unsigned Wo[4096];
    __shared__ __align__(16) unsigned char Vt[16384];   // [128 c'][64 j] bf16 (transposed)
    __shared__ __align__(16) unsigned char Ss[16384];   // [64 i][128 c'] bf16
    int tid = threadIdx.x;
    int ml = blockIdx.x, b = blockIdx.y;
    int mode = mbase + ml;
    bool dc = (mode == 0);
    int lane = tid & 63, w = tid >> 6;
    int lr = lane & 15, lg = lane >> 4;
    int wr = w & 1, wc = w >> 1;
    int sxa = (lr & 7) << 4;
    int ri = lr & 1;
    f32x4 zf = {0.f, 0.f, 0.f, 0.f};
    {   // stage Xs once
        const unsigned short* xg = XM + ((size_t)mode * 128 + b * 64) * 128;
        #pragma unroll
        for (int p = 0; p < 2; ++p) {
            int g = tid + p * 512; int row = g >> 4, c16 = g & 15;
            uint4 v = *(const uint4*)(xg + row * 128 + c16 * 8);
            *(uint4*)(Xs + row * 256 + ((c16 * 16) ^ ((row & 7) << 4))) = v;
        }
    }
    f32x4 oacc[2][2];
    oacc[0][0] = zf; oacc[0][1] = zf; oacc[1][0] = zf; oacc[1][1] = zf;
    for (int h = 0; h < NH; ++h) {
        __syncthreads();
        {   // stage Wv + Wo tiles
            const unsigned* tv = WV + ((size_t)(ml * 8 + h) << 12);
            const unsigned* to = WO + ((size_t)(ml * 8 + h) << 12);
            #pragma unroll
            for (int p = 0; p < 16; ++p) {
                int idx = tid + p * 512;
                int r = idx & 4095;
                int ci = r >> 6, co = r & 63;
                if (idx < 4096) Wv[ci * 64 + (co ^ ci)] = tv[r];
                else            Wo[ci * 64 + (co ^ ci)] = to[r];
            }
        }
        bf16x8 af[2][2];
        #pragma unroll
        for (int m = 0; m < 2; ++m)
            #pragma unroll
            for (int ks = 0; ks < 2; ++ks) {
                int irow = wr * 32 + m * 16 + lr;
                af[m][ks] = *(const bf16x8*)(attnb + (((size_t)(b * 8 + h) * 64 + irow) * 64 + ks * 32 + lg * 8));
            }
        __syncthreads();
        {   // Vtilde = Xs * WV' -> Vt transposed
            f32x4 va[2][2];
            va[0][0] = zf; va[0][1] = zf; va[1][0] = zf; va[1][1] = zf;
            #pragma unroll
            for (int ks = 0; ks < 4; ++ks) {
                int kb = (ks * 64 + lg * 16) ^ sxa;
                int ci0 = ks * 16 + lg * 4;
                bf16x8 a0 = *(const bf16x8*)(Xs + (wr * 32 + lr) * 256 + kb);
                bf16x8 a1 = *(const bf16x8*)(Xs + (wr * 32 + 16 + lr) * 256 + kb);
                #pragma unroll
                for (int n = 0; n < 2; ++n) {
                    int co_l = wc * 16 + n * 8 + (lr >> 1);
                    bf16x8 bb = mkfrag(Wv, co_l, ri, ci0, dc);
                    va[0][n] = MFMA_B16(a0, bb, va[0][n]);
                    va[1][n] = MFMA_B16(a1, bb, va[1][n]);
                }
            }
            #pragma unroll
            for (int m = 0; m < 2; ++m)
                #pragma unroll
                for (int n = 0; n < 2; ++n) {
                    int cp = wc * 32 + n * 16 + lr;
                    int j0 = wr * 32 + m * 16 + lg * 4;
                    uint2 t;
                    t.x = pack2(va[m][n][0], va[m][n][1]);
                    t.y = pack2(va[m][n][2], va[m][n][3]);
                    *(uint2*)(Vt + cp * 128 + ((j0 * 2) ^ ((cp & 7) << 4))) = t;
                }
        }
        __syncthreads();
        {   // SA = attn * Vtilde -> Ss
            f32x4 sa_[2][2];
            sa_[0][0] = zf; sa_[0][1] = zf; sa_[1][0] = zf; sa_[1][1] = zf;
            #pragma unroll
            for (int ks = 0; ks < 2; ++ks) {
                #pragma unroll
                for (int n = 0; n < 2; ++n) {
                    int cp = wc * 32 + n * 16 + lr;
                    bf16x8 bb = *(const bf16x8*)(Vt + cp * 128 + ((ks * 64 + lg * 16) ^ ((cp & 7) << 4)));
                    sa_[0][n] = MFMA_B16(af[0][ks], bb, sa_[0][n]);
                    sa_[1][n] = MFMA_B16(af[1][ks], bb, sa_[1][n]);
                }
            }
            #pragma unroll
            for (int m = 0; m < 2; ++m)
                #pragma unroll
                for (int n = 0; n < 2; ++n) {
                    int colb = (wc * 32 + n * 16 + lr) * 2;
                    #pragma unroll
                    for (int r = 0; r < 4; ++r) {
                        int row = wr * 32 + m * 16 + lg * 4 + r;
                        *(unsigned short*)(Ss + row * 256 + (colb ^ ((row & 7) << 4))) = f2b(sa_[m][n][r]);
                    }
                }
        }
        __syncthreads();
        {   // OUT += SA * WO'
            #pragma unroll
            for (int ks = 0; ks < 4; ++ks) {
                int kb = (ks * 64 + lg * 16) ^ sxa;
                int ci0 = ks * 16 + lg * 4;
                bf16x8 a0 = *(const bf16x8*)(Ss + (wr * 32 + lr) * 256 + kb);
                bf16x8 a1 = *(const bf16x8*)(Ss + (wr * 32 + 16 + lr) * 256 + kb);
                #pragma unroll
                for (int n = 0; n < 2; ++n) {
                    int co_l = wc * 16 + n * 8 + (lr >> 1);
                    bf16x8 bb = mkfrag(Wo, co_l, ri, ci0, false);
                    oacc[0][n] = MFMA_B16(a0, bb, oacc[0][n]);
                    oacc[1][n] = MFMA_B16(a1, bb, oacc[1][n]);
                }
            }
        }
    }
    #pragma unroll
    for (int m = 0; m < 2; ++m)
        #pragma unroll
        for (int n = 0; n < 2; ++n)
            #pragma unroll
            for (int r = 0; r < 4; ++r) {
                int i = wr * 32 + m * 16 + lg * 4 + r;
                int c2p = wc * 32 + n * 16 + lr;
                outf[((size_t)mode * 128 + b * 64 + i) * 128 + c2p] = oacc[m][n][r];
            }
}

// ---------- custom irfft2 of padded outf -> out f32 [bs][c2][32][32]
__global__ __launch_bounds__(256) void k_irfft(const float* __restrict__ outf,
                                               float* __restrict__ out) {
    __shared__ float c32[32], s32[32];
    __shared__ float mf[256][18];
    __shared__ float sr[16 * 33], si[16 * 33];
    int tid = threadIdx.x;
    int cg = blockIdx.x;   // 0..7
    int bs = blockIdx.y;   // 0..127
    if (tid < 32) { float s, c; __sincosf(TWO_PI * tid / 32.0f, &s, &c); c32[tid] = c; s32[tid] = s; }
    {
        const float4* gp = (const float4*)(outf + (((size_t)tid * 128 + bs) * 64 + cg * 8) * 2);
        for (int q = 0; q < 4; ++q) {
            float4 v = gp[q];
            mf[tid][q * 4 + 0] = v.x; mf[tid][q * 4 + 1] = v.y;
            mf[tid][q * 4 + 2] = v.z; mf[tid][q * 4 + 3] = v.w;
        }
    }
    __syncthreads();
    for (int cc = 0; cc < 8; ++cc) {
        for (int p = 0; p < 2; ++p) {
            int e = tid + p * 256;
            int u = e >> 5, y = e & 31;
            float fr0 = mf[u * 16][cc * 2];
            float fi0 = (u == 0) ? 0.f : mf[u * 16][cc * 2 + 1];
            float ssr = 0.5f * fr0, ssi = 0.5f * fi0;
            for (int v = 1; v < 16; ++v) {
                float fr = mf[u * 16 + v][cc * 2], fi = mf[u * 16 + v][cc * 2 + 1];
                int ph = (v * y) & 31;
                float c = c32[ph], s = s32[ph];
                ssr += fr * c - fi * s;
                ssi += fr * s + fi * c;
            }
            sr[u * 33 + y] = ssr; si[u * 33 + y] = ssi;
        }
        __syncthreads();
        float res[4];
        for (int p = 0; p < 4; ++p) {
            int pos = tid + p * 256;
            int x = pos >> 5, y = pos & 31;
            float acc = 0.f;
            for (int u = 0; u < 16; ++u) {
                int ph = (u * x) & 31;
                acc += sr[u * 33 + y] * c32[ph] - si[u * 33 + y] * s32[ph];
            }
            res[p] = acc * (1.0f / 512.0f);
        }
        float* op = out + ((size_t)(bs * 64 + cg * 8 + cc)) * 1024;
        for (int p = 0; p < 4; ++p) op[tid + p * 256] = res[p];
        __syncthreads();
    }
}

extern "C" void kernel_launch(void* const* d_in, const int* in_sizes, int n_in,
                              void* d_out, int out_size, void* d_ws, size_t ws_size,
                              hipStream_t stream) {
    (void)in_sizes; (void)n_in; (void)out_size;
    const float* seq = (const float*)d_in[0];
    const float* wq = (const float*)d_in[1];
    const float* wk = (const float*)d_in[2];
    const float* wv = (const float*)d_in[3];
    const float* wo = (const float*)d_in[4];
    const float* cw1 = (const float*)d_in[5];
    const float* cb1 = (const float*)d_in[6];
    const float* cw2 = (const float*)d_in[7];
    float* out = (float*)d_out;
    char* ws = (char*)d_ws;
    if (ws_size < WS_TOTAL) return;

    unsigned short* XM = (unsigned short*)(ws + OFF_XM);
    unsigned* WTA = (unsigned*)(ws + OFF_WTA);
    unsigned* WTB = (unsigned*)(ws + OFF_WTB);
    float* PART = (float*)(ws + OFF_PO);
    float* OUTF = (float*)(ws + OFF_PO);
    unsigned short* ATTNB = (unsigned short*)(ws + OFF_ATTN);

    k_rfft<<<dim3(8, 128), dim3(256), 0, stream>>>(seq, XM);

    for (int c = 0; c < NCH; ++c) {
        int m0 = c * CH;
        k_transpose2<<<dim3(512, CH / 16, 2), dim3(256), 0, stream>>>(wq, WTA, 0, wk, WTB, 0, m0);
        k_qks<<<dim3(CH / 4, NH, 2), dim3(512), 0, stream>>>(XM, WTA, WTB, PART, m0);
    }
    k_softmax<<<dim3(64, 16), dim3(64), 0, stream>>>(PART, cw1, cb1, cw2, ATTNB);

    for (int c = 0; c < NCH; ++c) {
        int m0 = c * CH;
        k_transpose2<<<dim3(512, CH / 16, 2), dim3(256), 0, stream>>>(wv, WTA, 1, wo, WTB, 2, m0);
        k_savo<<<dim3(CH, 2), dim3(512), 0, stream>>>(XM, WTA, WTB, ATTNB, OUTF, m0);
    }
    k_irfft<<<dim3(8, 128), dim3(256), 0, stream>>>(OUTF, out);
}

// Round 8
// 353.947 us; speedup vs baseline: 6.2701x; 1.0997x over previous
//
#include <hip/hip_runtime.h>

#define TWO_PI 6.28318530717958647692f

// dims
#define NH 8
#define CH 128     // modes per chunk
#define NCH 2

// workspace offsets (bytes), total ~56.25 MiB (proven-safe)
#define OFF_XM   0ull                        // bf16 [256][128][128]     8 MiB  (k'=2ci+ri interleaved)
#define OFF_WTA  (OFF_XM + 8388608ull)       // u32 tiles [CH][8][64][64] 16 MiB   (also T f32 [128][64][32][16]x2 = 32 MiB with WTB)
#define OFF_WTB  (OFF_WTA + 16777216ull)     // u32 tiles [CH][8][64][64] 16 MiB
#define OFF_PO   (OFF_WTB + 16777216ull)     // f32: PART [64][16][64][64] / OUTF [256][128][128]  16 MiB (shared)
#define OFF_ATTN (OFF_PO + 16777216ull)      // bf16 [16][64][64]
#define WS_TOTAL (OFF_ATTN + 262144ull)

typedef short bf16x8 __attribute__((ext_vector_type(8)));
typedef float f32x4 __attribute__((ext_vector_type(4)));
#define MFMA_B16(a, b, c) __builtin_amdgcn_mfma_f32_16x16x32_bf16(a, b, c, 0, 0, 0)

__device__ __forceinline__ float bl(unsigned u) { return __uint_as_float(u << 16); }
__device__ __forceinline__ unsigned short f2b(float f) {
    unsigned u = __float_as_uint(f);
    return (unsigned short)((u + 0x7fffu + ((u >> 16) & 1u)) >> 16);
}
__device__ __forceinline__ unsigned pack2(float lo, float hi) {
    return (unsigned)f2b(lo) | ((unsigned)f2b(hi) << 16);
}

// Build doubled-interleaved B-fragment from complex u32 tile Wt[ci][co^ci] (pitch 64).
// Row n = n0+lr: ri=n&1, co=n>>1. even: (Wr,-Wi); odd: (Wi,Wr); dc zeroes odd rows.
__device__ __forceinline__ bf16x8 mkfrag(const unsigned* __restrict__ Wt, int co_l, int ri,
                                         int ci0, bool dc) {
    unsigned a0 = Wt[(ci0 + 0) * 64 + (co_l ^ (ci0 + 0))];
    unsigned a1 = Wt[(ci0 + 1) * 64 + (co_l ^ (ci0 + 1))];
    unsigned a2 = Wt[(ci0 + 2) * 64 + (co_l ^ (ci0 + 2))];
    unsigned a3 = Wt[(ci0 + 3) * 64 + (co_l ^ (ci0 + 3))];
    uint4 r;
    if (ri) {
        if (dc) { r.x = 0u; r.y = 0u; r.z = 0u; r.w = 0u; }
        else {
            r.x = (a0 >> 16) | (a0 << 16); r.y = (a1 >> 16) | (a1 << 16);
            r.z = (a2 >> 16) | (a2 << 16); r.w = (a3 >> 16) | (a3 << 16);
        }
    } else {
        r.x = a0 ^ 0x80000000u; r.y = a1 ^ 0x80000000u;
        r.z = a2 ^ 0x80000000u; r.w = a3 ^ 0x80000000u;
    }
    return __builtin_bit_cast(bf16x8, r);
}

// ---------- weight transpose + Parseval prescale: f32 [R=32768][256][2] -> u32 tiles [ml][h][ci][co]
// kind 0: Q/K (sqrt2, layout ci*512+h*64+co), 1: V (1/2, same layout), 2: wo (none, layout h*4096+ci*64+co)
__global__ __launch_bounds__(256) void k_transpose2(const float* __restrict__ srcA, unsigned* __restrict__ dstA, int kindA,
                                                    const float* __restrict__ srcB, unsigned* __restrict__ dstB, int kindB,
                                                    int m0) {
    const float* in = (blockIdx.z == 0) ? srcA : srcB;
    unsigned* outp = (blockIdx.z == 0) ? dstA : dstB;
    int kind = (blockIdx.z == 0) ? kindA : kindB;
    __shared__ unsigned T[16][65];
    int tid = threadIdx.x;
    int r0 = blockIdx.x * 64;
    int ci, h;
    if (kind == 2) { h = r0 >> 12; ci = (r0 >> 6) & 63; }   // wo: r = h*4096 + ci*64 + co
    else           { ci = r0 >> 9; h = (r0 >> 6) & 7; }     // wq/wk/wv: r = ci*512 + h*64 + co
    int ml0 = blockIdx.y * 16;
    int u = (m0 + ml0) >> 4;
    const float2* in2 = (const float2*)in;
    #pragma unroll
    for (int p = 0; p < 4; ++p) {
        int f = tid + p * 256;
        int row = f >> 4, mc = f & 15;     // mc = v (mode col within 16-group)
        float fac = (kind == 0) ? (mc > 0 ? 1.41421356f : (u > 0 ? 0.70710678f : 1.f))
                  : (kind == 1) ? (mc > 0 ? 1.f : (u > 0 ? 0.5f : 1.f)) : 1.f;
        float2 v = in2[(size_t)(r0 + row) * 256 + m0 + ml0 + mc];
        T[mc][row] = pack2(v.x * fac, v.y * fac);
    }
    __syncthreads();
    #pragma unroll
    for (int p = 0; p < 4; ++p) {
        int f = tid + p * 256;
        int ml = f >> 6, co = f & 63;
        outp[((size_t)((ml0 + ml) * 8 + h) << 12) + ci * 64 + co] = T[ml][co];
    }
}

// ---------- rfft stage 1 (y-DFT): T[bs*64+ci][x][v] complex f32 = sum_y seq * e^{-i2pi vy/32}
__global__ __launch_bounds__(256) void k_rfft_y(const float* __restrict__ seq,
                                                float2* __restrict__ T) {
    __shared__ float c32[32], s32[32];
    __shared__ float fld[32][33];
    int tid = threadIdx.x;
    int bc = blockIdx.x;   // 0..8191 = bs*64+ci
    if (tid < 32) { float s, c; __sincosf(TWO_PI * tid / 32.0f, &s, &c); c32[tid] = c; s32[tid] = s; }
    float4 v = ((const float4*)(seq + (size_t)bc * 1024))[tid];
    int x = tid >> 3, y4 = (tid & 7) * 4;
    fld[x][y4] = v.x; fld[x][y4 + 1] = v.y; fld[x][y4 + 2] = v.z; fld[x][y4 + 3] = v.w;
    __syncthreads();
    float2* op = T + (size_t)bc * 512;
    #pragma unroll
    for (int p = 0; p < 2; ++p) {
        int e = tid + p * 256;
        int xx = e >> 4, vv = e & 15;
        float sr = 0.f, si = 0.f;
        #pragma unroll
        for (int y = 0; y < 32; ++y) {
            float f = fld[xx][y];
            int ph = (vv * y) & 31;
            sr = fmaf(f, c32[ph], sr);
            si = fmaf(-f, s32[ph], si);
        }
        float2 t; t.x = sr; t.y = si;
        op[e] = t;
    }
}

// ---------- rfft stage 2 (x-DFT): XM[mode][bs][2ci+ri] bf16 = sum_x T * e^{-i2pi ux/32}
__global__ __launch_bounds__(256) void k_rfft_x(const float2* __restrict__ T,
                                                unsigned short* __restrict__ XM) {
    __shared__ float c32[32], s32[32];
    __shared__ float2 t[8][512];
    int tid = threadIdx.x;
    int cig = blockIdx.x;   // 0..7
    int bs = blockIdx.y;    // 0..127
    if (tid < 32) { float s, c; __sincosf(TWO_PI * tid / 32.0f, &s, &c); c32[tid] = c; s32[tid] = s; }
    const float4* src = (const float4*)(T + ((size_t)bs * 64 + cig * 8) * 512);
    #pragma unroll
    for (int p = 0; p < 8; ++p) {
        int idx = tid + p * 256;            // float4 index, 2048 total
        float4 w = src[idx];
        int ch = idx >> 8, r2 = idx & 255;
        float2 t0; t0.x = w.x; t0.y = w.y;
        float2 t1; t1.x = w.z; t1.y = w.w;
        t[ch][r2 * 2] = t0; t[ch][r2 * 2 + 1] = t1;
    }
    __syncthreads();
    int u = tid >> 4, vv = tid & 15;
    unsigned outw[8];
    for (int ch = 0; ch < 8; ++ch) {
        float xr = 0.f, xi = 0.f;
        #pragma unroll
        for (int x = 0; x < 32; ++x) {
            float2 tv = t[ch][x * 16 + vv];
            int ph = (u * x) & 31;
            float c = c32[ph], s = s32[ph];
            xr += tv.x * c + tv.y * s;
            xi += tv.y * c - tv.x * s;
        }
        outw[ch] = pack2(xr, xi);
    }
    uint4* op = (uint4*)(XM + (((size_t)tid * 128 + bs) * 64 + cig * 8) * 2);
    uint4 a, b;
    a.x = outw[0]; a.y = outw[1]; a.z = outw[2]; a.w = outw[3];
    b.x = outw[4]; b.y = outw[5]; b.z = outw[6]; b.w = outw[7];
    op[0] = a; op[1] = b;
}

// ---------- fused MFMA Q/K modemix + scores: 512 threads, block=(mg of 4 modes, h, b)
__global__ __launch_bounds__(512) void k_qks(const unsigned short* __restrict__ XM,
                                             const unsigned* __restrict__ WQ,
                                             const unsigned* __restrict__ WK,
                                             float* __restrict__ part, int mbase) {
    __shared__ __align__(16) unsigned char Xs[16384];
    __shared__ __align__(16) unsigned Wq[4096];
    __shared__ __align__(16) unsigned Wk[4096];
    __shared__ __align__(16) unsigned char Qs[16384];
    __shared__ __align__(16) unsigned char Ks[16384];
    int tid = threadIdx.x;
    int mg = blockIdx.x, h = blockIdx.y, b = blockIdx.z;
    int lane = tid & 63, w = tid >> 6;
    int lr = lane & 15, lg = lane >> 4;
    int wr = w & 1, wc = w >> 1;          // wr 0..1, wc 0..3
    int sxa = (lr & 7) << 4;
    int ri = lr & 1;
    f32x4 zf = {0.f, 0.f, 0.f, 0.f};
    f32x4 sacc[2];
    sacc[0] = zf; sacc[1] = zf;
    for (int mm = 0; mm < 4; ++mm) {
        int ml = mg * 4 + mm;
        int mode = mbase + ml;
        bool dc = (mode == 0);
        __syncthreads();
        {   // stage Xs [64 tok][128 k'] swizzled
            const unsigned short* xg = XM + ((size_t)mode * 128 + b * 64) * 128;
            #pragma unroll
            for (int p = 0; p < 2; ++p) {
                int g = tid + p * 512; int row = g >> 4, c16 = g & 15;
                uint4 v = *(const uint4*)(xg + row * 128 + c16 * 8);
                *(uint4*)(Xs + row * 256 + ((c16 * 16) ^ ((row & 7) << 4))) = v;
            }
        }
        {   // stage Wq + Wk u32 tiles (16KB each, coalesced, swizzled placement co^ci)
            const unsigned* tq = WQ + ((size_t)(ml * 8 + h) << 12);
            const unsigned* tk = WK + ((size_t)(ml * 8 + h) << 12);
            #pragma unroll
            for (int p = 0; p < 16; ++p) {
                int idx = tid + p * 512;
                int r = idx & 4095;
                int ci = r >> 6, co = r & 63;
                if (idx < 4096) Wq[ci * 64 + (co ^ ci)] = tq[r];
                else            Wk[ci * 64 + (co ^ ci)] = tk[r];
            }
        }
        __syncthreads();
        {   // Qt = Xs*WQ' -> Qs ; Kt = Xs*WK' -> Ks
            f32x4 qa[2][2], ka[2][2];
            #pragma unroll
            for (int m = 0; m < 2; ++m)
                #pragma unroll
                for (int n = 0; n < 2; ++n) { qa[m][n] = zf; ka[m][n] = zf; }
            #pragma unroll
            for (int ks = 0; ks < 4; ++ks) {
                int kb = (ks * 64 + lg * 16) ^ sxa;
                int ci0 = ks * 16 + lg * 4;
                bf16x8 a0 = *(const bf16x8*)(Xs + (wr * 32 + lr) * 256 + kb);
                bf16x8 a1 = *(const bf16x8*)(Xs + (wr * 32 + 16 + lr) * 256 + kb);
                #pragma unroll
                for (int n = 0; n < 2; ++n) {
                    int co_l = wc * 16 + n * 8 + (lr >> 1);   // (n0+lr)>>1, n0=wc*32+n*16
                    bf16x8 bq = mkfrag(Wq, co_l, ri, ci0, dc);
                    bf16x8 bk = mkfrag(Wk, co_l, ri, ci0, dc);
                    qa[0][n] = MFMA_B16(a0, bq, qa[0][n]);
                    qa[1][n] = MFMA_B16(a1, bq, qa[1][n]);
                    ka[0][n] = MFMA_B16(a0, bk, ka[0][n]);
                    ka[1][n] = MFMA_B16(a1, bk, ka[1][n]);
                }
            }
            #pragma unroll
            for (int m = 0; m < 2; ++m)
                #pragma unroll
                for (int n = 0; n < 2; ++n) {
                    int colb = (wc * 32 + n * 16 + lr) * 2;
                    #pragma unroll
                    for (int r = 0; r < 4; ++r) {
                        int row = wr * 32 + m * 16 + lg * 4 + r;
                        int swz = (row & 7) << 4;
                        *(unsigned short*)(Qs + row * 256 + (colb ^ swz)) = f2b(qa[m][n][r]);
                        *(unsigned short*)(Ks + row * 256 + (colb ^ swz)) = f2b(ka[m][n][r]);
                    }
                }
        }
        __syncthreads();
        {   // scores: sacc += Qt(64x128) . Kt(64x128)^T
            #pragma unroll
            for (int ks = 0; ks < 4; ++ks) {
                int kb = (ks * 64 + lg * 16) ^ sxa;
                bf16x8 a0 = *(const bf16x8*)(Qs + (wr * 32 + lr) * 256 + kb);
                bf16x8 a1 = *(const bf16x8*)(Qs + (wr * 32 + 16 + lr) * 256 + kb);
                bf16x8 b0 = *(const bf16x8*)(Ks + (wc * 16 + lr) * 256 + kb);
                sacc[0] = MFMA_B16(a0, b0, sacc[0]);
                sacc[1] = MFMA_B16(a1, b0, sacc[1]);
            }
        }
    }
    float* pp = part + (((size_t)((mbase >> 2) + mg) * 16 + b * 8 + h) << 12);
    #pragma unroll
    for (int m = 0; m < 2; ++m)
        #pragma unroll
        for (int r = 0; r < 4; ++r)
            pp[(wr * 32 + m * 16 + lg * 4 + r) * 64 + wc * 16 + lr] = sacc[m][r];
}

// ---------- reduce partials + inline CPB bias + softmax -> attn bf16
__global__ void k_softmax(const float* __restrict__ part,
                          const float* __restrict__ w1, const float* __restrict__ b1,
                          const float* __restrict__ w2, unsigned short* __restrict__ attnb) {
    int j = threadIdx.x;   // 64
    int i = blockIdx.x;    // 64
    int bh = blockIdx.y;   // 16
    int h = bh & 7;
    float s = 0.f;
    for (int mg = 0; mg < 64; ++mg)
        s += part[(((size_t)mg * 16 + bh) * 64 + i) * 64 + j];
    float dx = (float)((i >> 3) - (j >> 3));
    float dy = (float)((i & 7) - (j & 7));
    float rx = (dx > 0.f ? 1.f : (dx < 0.f ? -1.f : 0.f)) * log1pf(fabsf(dx));
    float ry = (dy > 0.f ? 1.f : (dy < 0.f ? -1.f : 0.f)) * log1pf(fabsf(dy));
    float bias = 0.f;
    for (int l = 0; l < 64; ++l) {
        float hv = fmaxf(rx * w1[l] + ry * w1[64 + l] + b1[l], 0.f);
        bias = fmaf(hv, w2[l * NH + h], bias);
    }
    s = s * (1.0f / 262144.0f) + bias;
    float m = s;
    for (int o = 32; o >= 1; o >>= 1) m = fmaxf(m, __shfl_xor(m, o));
    float e = expf(s - m);
    float t = e;
    for (int o = 32; o >= 1; o >>= 1) t += __shfl_xor(t, o);
    attnb[((size_t)bh * 64 + i) * 64 + j] = f2b(e / t);
}

// ---------- fused MFMA V modemix + attn*V + wo: 512 threads, block=(mode_local, b)
__global__ __launch_bounds__(512) void k_savo(const unsigned short* __restrict__ XM,
                                              const unsigned* __restrict__ WV,
                                              const unsigned* __restrict__ WO,
                                              const unsigned short* __restrict__ attnb,
                                              float* __restrict__ outf, int mbase) {
    __shared__ __align__(16) unsigned char Xs[16384];
    __shared__ __align__(16) unsigned Wv[4096];
    __shared__ __align__(16) unsigned Wo[4096];
    __shared__ __align__(16) unsigned char Vt[16384];   // [128 c'][64 j] bf16 (transposed)
    __shared__ __align__(16) unsigned char Ss[16384];   // [64 i][128 c'] bf16
    int tid = threadIdx.x;
    int ml = blockIdx.x, b = blockIdx.y;
    int mode = mbase + ml;
    bool dc = (mode == 0);
    int lane = tid & 63, w = tid >> 6;
    int lr = lane & 15, lg = lane >> 4;
    int wr = w & 1, wc = w >> 1;
    int sxa = (lr & 7) << 4;
    int ri = lr & 1;
    f32x4 zf = {0.f, 0.f, 0.f, 0.f};
    {   // stage Xs once
        const unsigned short* xg = XM + ((size_t)mode * 128 + b * 64) * 128;
        #pragma unroll
        for (int p = 0; p < 2; ++p) {
            int g = tid + p * 512; int row = g >> 4, c16 = g & 15;
            uint4 v = *(const uint4*)(xg + row * 128 + c16 * 8);
            *(uint4*)(Xs + row * 256 + ((c16 * 16) ^ ((row & 7) << 4))) = v;
        }
    }
    f32x4 oacc[2][2];
    oacc[0][0] = zf; oacc[0][1] = zf; oacc[1][0] = zf; oacc[1][1] = zf;
    for (int h = 0; h < NH; ++h) {
        __syncthreads();
        {   // stage Wv + Wo tiles
            const unsigned* tv = WV + ((size_t)(ml * 8 + h) << 12);
            const unsigned* to = WO + ((size_t)(ml * 8 + h) << 12);
            #pragma unroll
            for (int p = 0; p < 16; ++p) {
                int idx = tid + p * 512;
                int r = idx & 4095;
                int ci = r >> 6, co = r & 63;
                if (idx < 4096) Wv[ci * 64 + (co ^ ci)] = tv[r];
                else            Wo[ci * 64 + (co ^ ci)] = to[r];
            }
        }
        bf16x8 af[2][2];
        #pragma unroll
        for (int m = 0; m < 2; ++m)
            #pragma unroll
            for (int ks = 0; ks < 2; ++ks) {
                int irow = wr * 32 + m * 16 + lr;
                af[m][ks] = *(const bf16x8*)(attnb + (((size_t)(b * 8 + h) * 64 + irow) * 64 + ks * 32 + lg * 8));
            }
        __syncthreads();
        {   // Vtilde = Xs * WV' -> Vt transposed
            f32x4 va[2][2];
            va[0][0] = zf; va[0][1] = zf; va[1][0] = zf; va[1][1] = zf;
            #pragma unroll
            for (int ks = 0; ks < 4; ++ks) {
                int kb = (ks * 64 + lg * 16) ^ sxa;
                int ci0 = ks * 16 + lg * 4;
                bf16x8 a0 = *(const bf16x8*)(Xs + (wr * 32 + lr) * 256 + kb);
                bf16x8 a1 = *(const bf16x8*)(Xs + (wr * 32 + 16 + lr) * 256 + kb);
                #pragma unroll
                for (int n = 0; n < 2; ++n) {
                    int co_l = wc * 16 + n * 8 + (lr >> 1);
                    bf16x8 bb = mkfrag(Wv, co_l, ri, ci0, dc);
                    va[0][n] = MFMA_B16(a0, bb, va[0][n]);
                    va[1][n] = MFMA_B16(a1, bb, va[1][n]);
                }
            }
            #pragma unroll
            for (int m = 0; m < 2; ++m)
                #pragma unroll
                for (int n = 0; n < 2; ++n) {
                    int cp = wc * 32 + n * 16 + lr;
                    int j0 = wr * 32 + m * 16 + lg * 4;
                    uint2 t;
                    t.x = pack2(va[m][n][0], va[m][n][1]);
                    t.y = pack2(va[m][n][2], va[m][n][3]);
                    *(uint2*)(Vt + cp * 128 + ((j0 * 2) ^ ((cp & 7) << 4))) = t;
                }
        }
        __syncthreads();
        {   // SA = attn * Vtilde -> Ss
            f32x4 sa_[2][2];
            sa_[0][0] = zf; sa_[0][1] = zf; sa_[1][0] = zf; sa_[1][1] = zf;
            #pragma unroll
            for (int ks = 0; ks < 2; ++ks) {
                #pragma unroll
                for (int n = 0; n < 2; ++n) {
                    int cp = wc * 32 + n * 16 + lr;
                    bf16x8 bb = *(const bf16x8*)(Vt + cp * 128 + ((ks * 64 + lg * 16) ^ ((cp & 7) << 4)));
                    sa_[0][n] = MFMA_B16(af[0][ks], bb, sa_[0][n]);
                    sa_[1][n] = MFMA_B16(af[1][ks], bb, sa_[1][n]);
                }
            }
            #pragma unroll
            for (int m = 0; m < 2; ++m)
                #pragma unroll
                for (int n = 0; n < 2; ++n) {
                    int colb = (wc * 32 + n * 16 + lr) * 2;
                    #pragma unroll
                    for (int r = 0; r < 4; ++r) {
                        int row = wr * 32 + m * 16 + lg * 4 + r;
                        *(unsigned short*)(Ss + row * 256 + (colb ^ ((row & 7) << 4))) = f2b(sa_[m][n][r]);
                    }
                }
        }
        __syncthreads();
        {   // OUT += SA * WO'
            #pragma unroll
            for (int ks = 0; ks < 4; ++ks) {
                int kb = (ks * 64 + lg * 16) ^ sxa;
                int ci0 = ks * 16 + lg * 4;
                bf16x8 a0 = *(const bf16x8*)(Ss + (wr * 32 + lr) * 256 + kb);
                bf16x8 a1 = *(const bf16x8*)(Ss + (wr * 32 + 16 + lr) * 256 + kb);
                #pragma unroll
                for (int n = 0; n < 2; ++n) {
                    int co_l = wc * 16 + n * 8 + (lr >> 1);
                    bf16x8 bb = mkfrag(Wo, co_l, ri, ci0, false);
                    oacc[0][n] = MFMA_B16(a0, bb, oacc[0][n]);
                    oacc[1][n] = MFMA_B16(a1, bb, oacc[1][n]);
                }
            }
        }
    }
    #pragma unroll
    for (int m = 0; m < 2; ++m)
        #pragma unroll
        for (int n = 0; n < 2; ++n)
            #pragma unroll
            for (int r = 0; r < 4; ++r) {
                int i = wr * 32 + m * 16 + lg * 4 + r;
                int c2p = wc * 32 + n * 16 + lr;
                outf[((size_t)mode * 128 + b * 64 + i) * 128 + c2p] = oacc[m][n][r];
            }
}

// ---------- custom irfft2 of padded outf -> out f32 [bs][c2][32][32]
__global__ __launch_bounds__(256) void k_irfft(const float* __restrict__ outf,
                                               float* __restrict__ out) {
    __shared__ float c32[32], s32[32];
    __shared__ float mf[256][18];
    __shared__ float sr[16 * 33], si[16 * 33];
    int tid = threadIdx.x;
    int cg = blockIdx.x;   // 0..7
    int bs = blockIdx.y;   // 0..127
    if (tid < 32) { float s, c; __sincosf(TWO_PI * tid / 32.0f, &s, &c); c32[tid] = c; s32[tid] = s; }
    {
        const float4* gp = (const float4*)(outf + (((size_t)tid * 128 + bs) * 64 + cg * 8) * 2);
        for (int q = 0; q < 4; ++q) {
            float4 v = gp[q];
            mf[tid][q * 4 + 0] = v.x; mf[tid][q * 4 + 1] = v.y;
            mf[tid][q * 4 + 2] = v.z; mf[tid][q * 4 + 3] = v.w;
        }
    }
    __syncthreads();
    for (int cc = 0; cc < 8; ++cc) {
        for (int p = 0; p < 2; ++p) {
            int e = tid + p * 256;
            int u = e >> 5, y = e & 31;
            float fr0 = mf[u * 16][cc * 2];
            float fi0 = (u == 0) ? 0.f : mf[u * 16][cc * 2 + 1];
            float ssr = 0.5f * fr0, ssi = 0.5f * fi0;
            for (int v = 1; v < 16; ++v) {
                float fr = mf[u * 16 + v][cc * 2], fi = mf[u * 16 + v][cc * 2 + 1];
                int ph = (v * y) & 31;
                float c = c32[ph], s = s32[ph];
                ssr += fr * c - fi * s;
                ssi += fr * s + fi * c;
            }
            sr[u * 33 + y] = ssr; si[u * 33 + y] = ssi;
        }
        __syncthreads();
        float res[4];
        for (int p = 0; p < 4; ++p) {
            int pos = tid + p * 256;
            int x = pos >> 5, y = pos & 31;
            float acc = 0.f;
            for (int u = 0; u < 16; ++u) {
                int ph = (u * x) & 31;
                acc += sr[u * 33 + y] * c32[ph] - si[u * 33 + y] * s32[ph];
            }
            res[p] = acc * (1.0f / 512.0f);
        }
        float* op = out + ((size_t)(bs * 64 + cg * 8 + cc)) * 1024;
        for (int p = 0; p < 4; ++p) op[tid + p * 256] = res[p];
        __syncthreads();
    }
}

extern "C" void kernel_launch(void* const* d_in, const int* in_sizes, int n_in,
                              void* d_out, int out_size, void* d_ws, size_t ws_size,
                              hipStream_t stream) {
    (void)in_sizes; (void)n_in; (void)out_size;
    const float* seq = (const float*)d_in[0];
    const float* wq = (const float*)d_in[1];
    const float* wk = (const float*)d_in[2];
    const float* wv = (const float*)d_in[3];
    const float* wo = (const float*)d_in[4];
    const float* cw1 = (const float*)d_in[5];
    const float* cb1 = (const float*)d_in[6];
    const float* cw2 = (const float*)d_in[7];
    float* out = (float*)d_out;
    char* ws = (char*)d_ws;
    if (ws_size < WS_TOTAL) return;

    unsigned short* XM = (unsigned short*)(ws + OFF_XM);
    unsigned* WTA = (unsigned*)(ws + OFF_WTA);
    unsigned* WTB = (unsigned*)(ws + OFF_WTB);
    float2* Tbuf = (float2*)(ws + OFF_WTA);   // 32 MiB overlay on WTA+WTB, dead before transposes
    float* PART = (float*)(ws + OFF_PO);
    float* OUTF = (float*)(ws + OFF_PO);
    unsigned short* ATTNB = (unsigned short*)(ws + OFF_ATTN);

    k_rfft_y<<<dim3(8192), dim3(256), 0, stream>>>(seq, Tbuf);
    k_rfft_x<<<dim3(8, 128), dim3(256), 0, stream>>>(Tbuf, XM);

    for (int c = 0; c < NCH; ++c) {
        int m0 = c * CH;
        k_transpose2<<<dim3(512, CH / 16, 2), dim3(256), 0, stream>>>(wq, WTA, 0, wk, WTB, 0, m0);
        k_qks<<<dim3(CH / 4, NH, 2), dim3(512), 0, stream>>>(XM, WTA, WTB, PART, m0);
    }
    k_softmax<<<dim3(64, 16), dim3(64), 0, stream>>>(PART, cw1, cb1, cw2, ATTNB);

    for (int c = 0; c < NCH; ++c) {
        int m0 = c * CH;
        k_transpose2<<<dim3(512, CH / 16, 2), dim3(256), 0, stream>>>(wv, WTA, 1, wo, WTB, 2, m0);
        k_savo<<<dim3(CH, 2), dim3(512), 0, stream>>>(XM, WTA, WTB, ATTNB, OUTF, m0);
    }
    k_irfft<<<dim3(8, 128), dim3(256), 0, stream>>>(OUTF, out);
}